// Round 2
// baseline (980.625 us; speedup 1.0000x reference)
//
#include <hip/hip_runtime.h>
#include <hip/hip_bf16.h>
#include <math.h>

#define H 128
#define FEAT 9

// ---------------- Atom encoder: h[v] = sum_f emb[f, x[v,f], :] ----------------
__global__ __launch_bounds__(256) void k_atom(const int* __restrict__ x,
    const float* __restrict__ emb, float* __restrict__ h,
    int N, int Npad, int maxv) {
  int wid = (blockIdx.x * blockDim.x + threadIdx.x) >> 6;
  int lane = threadIdx.x & 63;
  if (wid >= Npad) return;
  float a0 = 0.f, a1 = 0.f;
  if (wid < N) {
    const int* xr = x + (size_t)wid * FEAT;
#pragma unroll
    for (int f = 0; f < FEAT; ++f) {
      int id = xr[f];
      const float* e = emb + ((size_t)f * maxv + id) * H;
      a0 += e[lane];
      a1 += e[lane + 64];
    }
  }
  h[(size_t)wid * H + lane] = a0;
  h[(size_t)wid * H + 64 + lane] = a1;
}

// ---------------- degree count (by dst) ----------------
__global__ __launch_bounds__(256) void k_count(const int* __restrict__ dst,
    int* __restrict__ counts, int E) {
  int i = blockIdx.x * blockDim.x + threadIdx.x;
  if (i < E) atomicAdd(&counts[dst[i]], 1);
}

// ---------------- dinv = rsqrt(deg), deg = in_count + 1 (self loop) ----------------
__global__ __launch_bounds__(256) void k_dinv(const int* __restrict__ counts,
    float* __restrict__ dinv, int N) {
  int i = blockIdx.x * blockDim.x + threadIdx.x;
  if (i < N) dinv[i] = rsqrtf((float)(counts[i] + 1));
}

// ---------------- hierarchical scan: block-inclusive + block sums ----------------
__global__ __launch_bounds__(256) void k_scan1(const int* __restrict__ counts,
    int* __restrict__ incl, int* __restrict__ bsum, int n) {
  __shared__ int ws[4];
  int t = threadIdx.x;
  int i = blockIdx.x * 256 + t;
  int lane = t & 63, w = t >> 6;
  int v = (i < n) ? counts[i] : 0;
  int s = v;
#pragma unroll
  for (int off = 1; off < 64; off <<= 1) {
    int u = __shfl_up(s, off, 64);
    if (lane >= off) s += u;
  }
  if (lane == 63) ws[w] = s;
  __syncthreads();
  if (t == 0) {
    int acc = 0;
#pragma unroll
    for (int j = 0; j < 4; ++j) { int tmp = ws[j]; ws[j] = acc; acc += tmp; }
  }
  __syncthreads();
  s += ws[w];
  if (i < n) incl[i] = s;
  if (t == 255) bsum[blockIdx.x] = s;
}

// exclusive scan of block sums in-place (nb <= 256)
__global__ __launch_bounds__(256) void k_scan2(int* __restrict__ bsum, int nb) {
  __shared__ int ws[4];
  int t = threadIdx.x, lane = t & 63, w = t >> 6;
  int v = (t < nb) ? bsum[t] : 0;
  int s = v;
#pragma unroll
  for (int off = 1; off < 64; off <<= 1) {
    int u = __shfl_up(s, off, 64);
    if (lane >= off) s += u;
  }
  if (lane == 63) ws[w] = s;
  __syncthreads();
  if (t == 0) {
    int acc = 0;
#pragma unroll
    for (int j = 0; j < 4; ++j) { int tmp = ws[j]; ws[j] = acc; acc += tmp; }
  }
  __syncthreads();
  s += ws[w];
  if (t < nb) bsum[t] = s - v;   // exclusive
}

__global__ __launch_bounds__(256) void k_scan3(const int* __restrict__ incl,
    const int* __restrict__ boff, int* __restrict__ row_ptr, int n) {
  int i = blockIdx.x * 256 + threadIdx.x;
  if (i < n) row_ptr[i + 1] = incl[i] + boff[i >> 8];
  if (i == 0) row_ptr[0] = 0;
}

// ---------------- CSR fill: col[row_ptr[dst]+k] = src ----------------
__global__ __launch_bounds__(256) void k_fill(const int* __restrict__ src,
    const int* __restrict__ dst, const int* __restrict__ row_ptr,
    int* __restrict__ cursor, int* __restrict__ col, int E) {
  int i = blockIdx.x * blockDim.x + threadIdx.x;
  if (i < E) {
    int d = dst[i];
    int pos = atomicAdd(&cursor[d], 1);
    col[row_ptr[d] + pos] = src[i];
  }
}

// ---------------- fp32 GEMM: C[Npad x 128] = A[Npad x 128] @ W[128 x 128] ----------------
// 128x128 block tile, 8x8 per thread as two 4-row/4-col quads 64 apart (2-way
// bank aliasing on all ds_read_b128 = free). A staged transposed.
__global__ __launch_bounds__(256) void k_gemm(const float* __restrict__ A,
    const float* __restrict__ W, float* __restrict__ C) {
  __shared__ float sAT[64][132];  // [k][row]
  __shared__ float sB[64][132];   // [k][col]
  int t = threadIdx.x;
  int row0 = blockIdx.x * 128;
  int tr = (t >> 4) << 2;        // 0..60
  int tc = (t & 15) << 2;        // 0..60
  float acc[8][8];
#pragma unroll
  for (int i = 0; i < 8; ++i)
#pragma unroll
    for (int j = 0; j < 8; ++j) acc[i][j] = 0.f;

  for (int kt = 0; kt < 2; ++kt) {
    // stage A (transposed): 128 rows x 64 k
#pragma unroll
    for (int it = 0; it < 8; ++it) {
      int i = t + it * 256;
      int r = i >> 4;
      int k4 = (i & 15) << 2;
      float4 v = *(const float4*)(A + (size_t)(row0 + r) * H + kt * 64 + k4);
      sAT[k4 + 0][r] = v.x; sAT[k4 + 1][r] = v.y;
      sAT[k4 + 2][r] = v.z; sAT[k4 + 3][r] = v.w;
    }
    // stage W: 64 k x 128 cols
#pragma unroll
    for (int it = 0; it < 8; ++it) {
      int i = t + it * 256;
      int k = i >> 5;
      int n4 = (i & 31) << 2;
      *(float4*)&sB[k][n4] = *(const float4*)(W + (size_t)(kt * 64 + k) * H + n4);
    }
    __syncthreads();
#pragma unroll 4
    for (int k = 0; k < 64; ++k) {
      float4 a0 = *(float4*)&sAT[k][tr];
      float4 a1 = *(float4*)&sAT[k][tr + 64];
      float4 b0 = *(float4*)&sB[k][tc];
      float4 b1 = *(float4*)&sB[k][tc + 64];
      float av[8] = {a0.x, a0.y, a0.z, a0.w, a1.x, a1.y, a1.z, a1.w};
      float bv[8] = {b0.x, b0.y, b0.z, b0.w, b1.x, b1.y, b1.z, b1.w};
#pragma unroll
      for (int i = 0; i < 8; ++i)
#pragma unroll
        for (int j = 0; j < 8; ++j) acc[i][j] += av[i] * bv[j];
    }
    __syncthreads();
  }
#pragma unroll
  for (int i = 0; i < 8; ++i) {
    int r = row0 + ((i < 4) ? (tr + i) : (64 + tr + i - 4));
    float4 o0 = {acc[i][0], acc[i][1], acc[i][2], acc[i][3]};
    float4 o1 = {acc[i][4], acc[i][5], acc[i][6], acc[i][7]};
    *(float4*)(C + (size_t)r * H + tc) = o0;
    *(float4*)(C + (size_t)r * H + 64 + tc) = o1;
  }
}

// ---------------- channel-chunked aggregate + bias + relu + BN stats ----------------
// chunk = blockIdx % 8 -> XCD affinity; per-chunk m working set 3.2MB fits 4MB L2.
// Wave: lane = sub*16 + ch; 4 edges in flight; shfl_xor reduce.
__global__ __launch_bounds__(256) void k_agg(const float* __restrict__ m,
    const int* __restrict__ row_ptr, const int* __restrict__ col,
    const float* __restrict__ dinv, const float* __restrict__ bias,
    float* __restrict__ a, float* __restrict__ bn_sum, float* __restrict__ bn_sq,
    int N) {
  __shared__ float s_sum[16], s_sq[16];
  int t = threadIdx.x;
  if (t < 16) { s_sum[t] = 0.f; s_sq[t] = 0.f; }
  __syncthreads();
  int chunk = blockIdx.x & 7;
  int c0 = chunk << 4;
  int lane = t & 63;
  int ch = lane & 15;
  int sub = lane >> 4;
  int wavesPerChunk = (gridDim.x >> 3) << 2;
  int waveIdx = ((blockIdx.x >> 3) << 2) + (t >> 6);
  float b = bias[c0 + ch];
  float lsum = 0.f, lsq = 0.f;
  for (int v = waveIdx; v < N; v += wavesPerChunk) {
    int s0 = row_ptr[v], s1 = row_ptr[v + 1];
    float dv = dinv[v];
    float acc = (sub == 0) ? dv * m[(size_t)v * H + c0 + ch] : 0.f;
    for (int s = s0 + sub; s < s1; s += 4) {
      int u = col[s];
      acc += dinv[u] * m[(size_t)u * H + c0 + ch];
    }
    acc += __shfl_xor(acc, 16, 64);
    acc += __shfl_xor(acc, 32, 64);
    if (sub == 0) {
      float av = fmaxf(dv * acc + b, 0.f);
      a[(size_t)v * H + c0 + ch] = av;
      lsum += av; lsq += av * av;
    }
  }
  if (sub == 0) { atomicAdd(&s_sum[ch], lsum); atomicAdd(&s_sq[ch], lsq); }
  __syncthreads();
  if (t < 16) {
    atomicAdd(&bn_sum[c0 + t], s_sum[t]);
    atomicAdd(&bn_sq[c0 + t], s_sq[t]);
  }
}

// ---------------- BN finalize + relu + residual (in-place h) ----------------
__global__ __launch_bounds__(256) void k_bn(const float* __restrict__ a,
    float* __restrict__ h, const float* __restrict__ bn_sum,
    const float* __restrict__ bn_sq, const float* __restrict__ gamma,
    const float* __restrict__ beta, int N) {
  int idx = blockIdx.x * blockDim.x + threadIdx.x;   // float4 index over N*32
  int total = N * 32;
  if (idx >= total) return;
  int c4 = idx & 31;
  float invN = 1.0f / (float)N;
  float4 s = *(const float4*)(bn_sum + c4 * 4);
  float4 q = *(const float4*)(bn_sq + c4 * 4);
  float4 g = *(const float4*)(gamma + c4 * 4);
  float4 be = *(const float4*)(beta + c4 * 4);
  float4 av = *(const float4*)(a + (size_t)idx * 4);
  float4 hv = *(const float4*)(h + (size_t)idx * 4);
  float4 o;
  {
    float mean = s.x * invN; float var = q.x * invN - mean * mean;
    float sc = g.x * rsqrtf(var + 1e-5f);
    o.x = fmaxf(sc * (av.x - mean) + be.x, 0.f) + hv.x;
  }
  {
    float mean = s.y * invN; float var = q.y * invN - mean * mean;
    float sc = g.y * rsqrtf(var + 1e-5f);
    o.y = fmaxf(sc * (av.y - mean) + be.y, 0.f) + hv.y;
  }
  {
    float mean = s.z * invN; float var = q.z * invN - mean * mean;
    float sc = g.z * rsqrtf(var + 1e-5f);
    o.z = fmaxf(sc * (av.z - mean) + be.z, 0.f) + hv.z;
  }
  {
    float mean = s.w * invN; float var = q.w * invN - mean * mean;
    float sc = g.w * rsqrtf(var + 1e-5f);
    o.w = fmaxf(sc * (av.w - mean) + be.w, 0.f) + hv.w;
  }
  *(float4*)(h + (size_t)idx * 4) = o;
}

// ---------------- mean-pool readout (atomic) ----------------
__global__ __launch_bounds__(256) void k_pool(const float* __restrict__ h,
    const int* __restrict__ batch, float* __restrict__ pooled,
    float* __restrict__ gcnt, int N) {
  int wid = (blockIdx.x * blockDim.x + threadIdx.x) >> 6;
  int lane = threadIdx.x & 63;
  if (wid >= N) return;
  int g = batch[wid];
  atomicAdd(&pooled[(size_t)g * H + lane], h[(size_t)wid * H + lane]);
  atomicAdd(&pooled[(size_t)g * H + 64 + lane], h[(size_t)wid * H + 64 + lane]);
  if (lane == 0) atomicAdd(&gcnt[g], 1.0f);
}

// ---------------- final: sigmoid(pooled/cnt @ lin_W + lin_b) ----------------
__global__ __launch_bounds__(256) void k_out(const float* __restrict__ pooled,
    const float* __restrict__ gcnt, const float* __restrict__ lw,
    const float* __restrict__ lb, float* __restrict__ out, int G) {
  int wid = (blockIdx.x * blockDim.x + threadIdx.x) >> 6;
  int lane = threadIdx.x & 63;
  if (wid >= G) return;
  float inv = 1.f / fmaxf(gcnt[wid], 1.f);
  float s = pooled[(size_t)wid * H + lane] * inv * lw[lane]
          + pooled[(size_t)wid * H + 64 + lane] * inv * lw[64 + lane];
#pragma unroll
  for (int off = 32; off > 0; off >>= 1) s += __shfl_down(s, off, 64);
  if (lane == 0) out[wid] = 1.f / (1.f + expf(-(s + lb[0])));
}

extern "C" void kernel_launch(void* const* d_in, const int* in_sizes, int n_in,
                              void* d_out, int out_size, void* d_ws, size_t ws_size,
                              hipStream_t stream) {
  const int* x      = (const int*)d_in[0];
  const int* ei     = (const int*)d_in[1];
  const int* batch  = (const int*)d_in[2];
  const float* emb  = (const float*)d_in[3];
  const float* convW = (const float*)d_in[4];
  const float* convB = (const float*)d_in[5];
  const float* gamma = (const float*)d_in[6];
  const float* beta  = (const float*)d_in[7];
  const float* lw    = (const float*)d_in[8];
  const float* lb    = (const float*)d_in[9];
  float* out = (float*)d_out;

  const int N = in_sizes[2];
  const int E = in_sizes[1] / 2;
  const int G = out_size;
  const int MAXV = in_sizes[3] / (FEAT * H);
  const int L = in_sizes[4] / (H * H);
  const int Npad = (N + 127) & ~127;          // 128-row GEMM tiles

  const int* srcp = ei;
  const int* dstp = ei + E;

  char* p = (char*)d_ws;
  auto alloc = [&](size_t bytes) { char* r = p; p += (bytes + 255) & ~255ull; return r; };
  float* h    = (float*)alloc((size_t)Npad * H * 4);
  float* m    = (float*)alloc((size_t)Npad * H * 4);
  float* a    = (float*)alloc((size_t)Npad * H * 4);
  float* dinv = (float*)alloc((size_t)N * 4);
  int* row_ptr = (int*)alloc((size_t)(N + 1) * 4);
  int* col     = (int*)alloc((size_t)E * 4);
  int* incl    = (int*)alloc((size_t)N * 4);
  int* bsum    = (int*)alloc(256 * 4);
  char* z0 = p;
  int* counts   = (int*)alloc((size_t)N * 4);
  int* cursor   = (int*)alloc((size_t)N * 4);
  float* bn_sum = (float*)alloc((size_t)L * H * 4);
  float* bn_sq  = (float*)alloc((size_t)L * H * 4);
  float* pooled = (float*)alloc((size_t)G * H * 4);
  float* gcnt   = (float*)alloc((size_t)G * 4);
  size_t zbytes = (size_t)(p - z0);

  hipMemsetAsync(z0, 0, zbytes, stream);

  const int nb = (N + 255) / 256;

  // graph prep
  k_atom<<<Npad / 4, 256, 0, stream>>>(x, emb, h, N, Npad, MAXV);
  k_count<<<(E + 255) / 256, 256, 0, stream>>>(dstp, counts, E);
  k_dinv<<<(N + 255) / 256, 256, 0, stream>>>(counts, dinv, N);
  k_scan1<<<nb, 256, 0, stream>>>(counts, incl, bsum, N);
  k_scan2<<<1, 256, 0, stream>>>(bsum, nb);
  k_scan3<<<nb, 256, 0, stream>>>(incl, bsum, row_ptr, N);
  k_fill<<<(E + 255) / 256, 256, 0, stream>>>(srcp, dstp, row_ptr, cursor, col, E);

  // layers
  for (int l = 0; l < L; ++l) {
    k_gemm<<<Npad / 128, 256, 0, stream>>>(h, convW + (size_t)l * H * H, m);
    k_agg<<<2048, 256, 0, stream>>>(m, row_ptr, col, dinv, convB + (size_t)l * H,
                                    a, bn_sum + (size_t)l * H, bn_sq + (size_t)l * H, N);
    k_bn<<<(N * 32 + 255) / 256, 256, 0, stream>>>(a, h, bn_sum + (size_t)l * H,
                                                   bn_sq + (size_t)l * H,
                                                   gamma + (size_t)l * H,
                                                   beta + (size_t)l * H, N);
  }

  // readout
  k_pool<<<(N + 3) / 4, 256, 0, stream>>>(h, batch, pooled, gcnt, N);
  k_out<<<(G + 3) / 4, 256, 0, stream>>>(pooled, gcnt, lw, lb, out, G);
}

// Round 3
// 673.412 us; speedup vs baseline: 1.4562x; 1.4562x over previous
//
#include <hip/hip_runtime.h>
#include <hip/hip_bf16.h>
#include <math.h>

#define H 128
#define FEAT 9

typedef unsigned int uint;

// round-to-nearest-even f32 -> bf16 (finite inputs)
__device__ inline uint f2bf(float f) {
  uint u = __float_as_uint(f);
  return (u + 0x7FFF + ((u >> 16) & 1)) >> 16;
}
__device__ inline uint pk_bf16(float a, float b) {
  return f2bf(a) | (f2bf(b) << 16);
}
#define BLO(u) __uint_as_float((u) << 16)
#define BHI(u) __uint_as_float((u) & 0xFFFF0000u)

// ---------------- Atom encoder: h[v] = sum_f emb[f, x[v,f], :] ----------------
__global__ __launch_bounds__(256) void k_atom(const int* __restrict__ x,
    const float* __restrict__ emb, float* __restrict__ h,
    int N, int Npad, int maxv) {
  int wid = (blockIdx.x * blockDim.x + threadIdx.x) >> 6;
  int lane = threadIdx.x & 63;
  if (wid >= Npad) return;
  float a0 = 0.f, a1 = 0.f;
  if (wid < N) {
    const int* xr = x + (size_t)wid * FEAT;
#pragma unroll
    for (int f = 0; f < FEAT; ++f) {
      int id = xr[f];
      const float* e = emb + ((size_t)f * maxv + id) * H;
      a0 += e[lane];
      a1 += e[lane + 64];
    }
  }
  h[(size_t)wid * H + lane] = a0;
  h[(size_t)wid * H + 64 + lane] = a1;
}

// ---------------- degree count (by dst) ----------------
__global__ __launch_bounds__(256) void k_count(const int* __restrict__ dst,
    int* __restrict__ counts, int E) {
  int i = blockIdx.x * blockDim.x + threadIdx.x;
  if (i < E) atomicAdd(&counts[dst[i]], 1);
}

// ---------------- dinv = rsqrt(deg), deg = in_count + 1 (self loop) ----------------
__global__ __launch_bounds__(256) void k_dinv(const int* __restrict__ counts,
    float* __restrict__ dinv, int N) {
  int i = blockIdx.x * blockDim.x + threadIdx.x;
  if (i < N) dinv[i] = rsqrtf((float)(counts[i] + 1));
}

// ---------------- hierarchical scan ----------------
__global__ __launch_bounds__(256) void k_scan1(const int* __restrict__ counts,
    int* __restrict__ incl, int* __restrict__ bsum, int n) {
  __shared__ int ws[4];
  int t = threadIdx.x;
  int i = blockIdx.x * 256 + t;
  int lane = t & 63, w = t >> 6;
  int v = (i < n) ? counts[i] : 0;
  int s = v;
#pragma unroll
  for (int off = 1; off < 64; off <<= 1) {
    int u = __shfl_up(s, off, 64);
    if (lane >= off) s += u;
  }
  if (lane == 63) ws[w] = s;
  __syncthreads();
  if (t == 0) {
    int acc = 0;
#pragma unroll
    for (int j = 0; j < 4; ++j) { int tmp = ws[j]; ws[j] = acc; acc += tmp; }
  }
  __syncthreads();
  s += ws[w];
  if (i < n) incl[i] = s;
  if (t == 255) bsum[blockIdx.x] = s;
}

__global__ __launch_bounds__(256) void k_scan2(int* __restrict__ bsum, int nb) {
  __shared__ int ws[4];
  int t = threadIdx.x, lane = t & 63, w = t >> 6;
  int v = (t < nb) ? bsum[t] : 0;
  int s = v;
#pragma unroll
  for (int off = 1; off < 64; off <<= 1) {
    int u = __shfl_up(s, off, 64);
    if (lane >= off) s += u;
  }
  if (lane == 63) ws[w] = s;
  __syncthreads();
  if (t == 0) {
    int acc = 0;
#pragma unroll
    for (int j = 0; j < 4; ++j) { int tmp = ws[j]; ws[j] = acc; acc += tmp; }
  }
  __syncthreads();
  s += ws[w];
  if (t < nb) bsum[t] = s - v;   // exclusive
}

__global__ __launch_bounds__(256) void k_scan3(const int* __restrict__ incl,
    const int* __restrict__ boff, int* __restrict__ row_ptr, int n) {
  int i = blockIdx.x * 256 + threadIdx.x;
  if (i < n) row_ptr[i + 1] = incl[i] + boff[i >> 8];
  if (i == 0) row_ptr[0] = 0;
}

// ---------------- CSR fill ----------------
__global__ __launch_bounds__(256) void k_fill(const int* __restrict__ src,
    const int* __restrict__ dst, const int* __restrict__ row_ptr,
    int* __restrict__ cursor, int* __restrict__ col, int E) {
  int i = blockIdx.x * blockDim.x + threadIdx.x;
  if (i < E) {
    int d = dst[i];
    int pos = atomicAdd(&cursor[d], 1);
    col[row_ptr[d] + pos] = src[i];
  }
}

// ---------------- fp32 GEMM + epilogue: ms = bf16(dinv * (A@W)) ----------------
// 128x128 block tile, 8x8/thread as two 4x4 quads 64 apart.
__global__ __launch_bounds__(256) void k_gemm(const float* __restrict__ A,
    const float* __restrict__ W, uint* __restrict__ ms,
    const float* __restrict__ dinv, int N) {
  __shared__ float sAT[64][132];  // [k][row]
  __shared__ float sB[64][132];   // [k][col]
  int t = threadIdx.x;
  int row0 = blockIdx.x * 128;
  int tr = (t >> 4) << 2;
  int tc = (t & 15) << 2;
  float acc[8][8];
#pragma unroll
  for (int i = 0; i < 8; ++i)
#pragma unroll
    for (int j = 0; j < 8; ++j) acc[i][j] = 0.f;

  for (int kt = 0; kt < 2; ++kt) {
#pragma unroll
    for (int it = 0; it < 8; ++it) {
      int i = t + it * 256;
      int r = i >> 4;
      int k4 = (i & 15) << 2;
      float4 v = *(const float4*)(A + (size_t)(row0 + r) * H + kt * 64 + k4);
      sAT[k4 + 0][r] = v.x; sAT[k4 + 1][r] = v.y;
      sAT[k4 + 2][r] = v.z; sAT[k4 + 3][r] = v.w;
    }
#pragma unroll
    for (int it = 0; it < 8; ++it) {
      int i = t + it * 256;
      int k = i >> 5;
      int n4 = (i & 31) << 2;
      *(float4*)&sB[k][n4] = *(const float4*)(W + (size_t)(kt * 64 + k) * H + n4);
    }
    __syncthreads();
#pragma unroll 4
    for (int k = 0; k < 64; ++k) {
      float4 a0 = *(float4*)&sAT[k][tr];
      float4 a1 = *(float4*)&sAT[k][tr + 64];
      float4 b0 = *(float4*)&sB[k][tc];
      float4 b1 = *(float4*)&sB[k][tc + 64];
      float av[8] = {a0.x, a0.y, a0.z, a0.w, a1.x, a1.y, a1.z, a1.w};
      float bv[8] = {b0.x, b0.y, b0.z, b0.w, b1.x, b1.y, b1.z, b1.w};
#pragma unroll
      for (int i = 0; i < 8; ++i)
#pragma unroll
        for (int j = 0; j < 8; ++j) acc[i][j] += av[i] * bv[j];
    }
    __syncthreads();
  }
#pragma unroll
  for (int i = 0; i < 8; ++i) {
    int r = row0 + ((i < 4) ? (tr + i) : (64 + tr + i - 4));
    float dr = (r < N) ? dinv[r] : 0.f;
    uint2 o0, o1;
    o0.x = pk_bf16(acc[i][0] * dr, acc[i][1] * dr);
    o0.y = pk_bf16(acc[i][2] * dr, acc[i][3] * dr);
    o1.x = pk_bf16(acc[i][4] * dr, acc[i][5] * dr);
    o1.y = pk_bf16(acc[i][6] * dr, acc[i][7] * dr);
    *(uint2*)(ms + (size_t)r * 64 + (tc >> 1)) = o0;
    *(uint2*)(ms + (size_t)r * 64 + 32 + (tc >> 1)) = o1;
  }
}

// ---------------- aggregate: a = relu(dinv_v * sum(ms) + b), BN stats ----------------
// ms[u] = bf16x2(dinv_u * m[u]); one 4B load per edge per lane, unroll x4.
__global__ __launch_bounds__(256) void k_agg(const uint* __restrict__ ms,
    const int* __restrict__ row_ptr, const int* __restrict__ col,
    const float* __restrict__ dinv, const float* __restrict__ bias,
    float* __restrict__ a, float* __restrict__ bn_sum, float* __restrict__ bn_sq,
    int N) {
  __shared__ float s_sum[128], s_sq[128];
  for (int i = threadIdx.x; i < 128; i += 256) { s_sum[i] = 0.f; s_sq[i] = 0.f; }
  __syncthreads();
  int lane = threadIdx.x & 63;
  int wid = (blockIdx.x * 256 + threadIdx.x) >> 6;
  int nw = (gridDim.x * 256) >> 6;
  float b0 = bias[2 * lane], b1 = bias[2 * lane + 1];
  float lsum0 = 0.f, lsq0 = 0.f, lsum1 = 0.f, lsq1 = 0.f;
  for (int v = wid; v < N; v += nw) {
    int s0 = row_ptr[v], s1 = row_ptr[v + 1];
    float dv = dinv[v];
    uint sv = ms[(size_t)v * 64 + lane];
    float acc0 = BLO(sv), acc1 = BHI(sv);
    int s = s0;
    for (; s + 4 <= s1; s += 4) {
      int u0 = col[s], u1 = col[s + 1], u2 = col[s + 2], u3 = col[s + 3];
      uint w0 = ms[(size_t)u0 * 64 + lane];
      uint w1 = ms[(size_t)u1 * 64 + lane];
      uint w2 = ms[(size_t)u2 * 64 + lane];
      uint w3 = ms[(size_t)u3 * 64 + lane];
      acc0 += BLO(w0) + BLO(w1) + BLO(w2) + BLO(w3);
      acc1 += BHI(w0) + BHI(w1) + BHI(w2) + BHI(w3);
    }
    for (; s < s1; ++s) {
      uint w = ms[(size_t)col[s] * 64 + lane];
      acc0 += BLO(w);
      acc1 += BHI(w);
    }
    float a0 = fmaxf(dv * acc0 + b0, 0.f);
    float a1 = fmaxf(dv * acc1 + b1, 0.f);
    float2 av = {a0, a1};
    *(float2*)(a + (size_t)v * H + 2 * lane) = av;
    lsum0 += a0; lsq0 += a0 * a0;
    lsum1 += a1; lsq1 += a1 * a1;
  }
  atomicAdd(&s_sum[2 * lane], lsum0);
  atomicAdd(&s_sum[2 * lane + 1], lsum1);
  atomicAdd(&s_sq[2 * lane], lsq0);
  atomicAdd(&s_sq[2 * lane + 1], lsq1);
  __syncthreads();
  for (int i = threadIdx.x; i < 128; i += 256) {
    atomicAdd(&bn_sum[i], s_sum[i]);
    atomicAdd(&bn_sq[i], s_sq[i]);
  }
}

// ---------------- BN finalize + relu + residual (in-place h) ----------------
__global__ __launch_bounds__(256) void k_bn(const float* __restrict__ a,
    float* __restrict__ h, const float* __restrict__ bn_sum,
    const float* __restrict__ bn_sq, const float* __restrict__ gamma,
    const float* __restrict__ beta, int N) {
  int idx = blockIdx.x * blockDim.x + threadIdx.x;   // float4 index over N*32
  int total = N * 32;
  if (idx >= total) return;
  int c4 = idx & 31;
  float invN = 1.0f / (float)N;
  float4 s = *(const float4*)(bn_sum + c4 * 4);
  float4 q = *(const float4*)(bn_sq + c4 * 4);
  float4 g = *(const float4*)(gamma + c4 * 4);
  float4 be = *(const float4*)(beta + c4 * 4);
  float4 av = *(const float4*)(a + (size_t)idx * 4);
  float4 hv = *(const float4*)(h + (size_t)idx * 4);
  float4 o;
  {
    float mean = s.x * invN; float var = q.x * invN - mean * mean;
    float sc = g.x * rsqrtf(var + 1e-5f);
    o.x = fmaxf(sc * (av.x - mean) + be.x, 0.f) + hv.x;
  }
  {
    float mean = s.y * invN; float var = q.y * invN - mean * mean;
    float sc = g.y * rsqrtf(var + 1e-5f);
    o.y = fmaxf(sc * (av.y - mean) + be.y, 0.f) + hv.y;
  }
  {
    float mean = s.z * invN; float var = q.z * invN - mean * mean;
    float sc = g.z * rsqrtf(var + 1e-5f);
    o.z = fmaxf(sc * (av.z - mean) + be.z, 0.f) + hv.z;
  }
  {
    float mean = s.w * invN; float var = q.w * invN - mean * mean;
    float sc = g.w * rsqrtf(var + 1e-5f);
    o.w = fmaxf(sc * (av.w - mean) + be.w, 0.f) + hv.w;
  }
  *(float4*)(h + (size_t)idx * 4) = o;
}

// ---------------- mean-pool readout (atomic) ----------------
__global__ __launch_bounds__(256) void k_pool(const float* __restrict__ h,
    const int* __restrict__ batch, float* __restrict__ pooled,
    float* __restrict__ gcnt, int N) {
  int wid = (blockIdx.x * blockDim.x + threadIdx.x) >> 6;
  int lane = threadIdx.x & 63;
  if (wid >= N) return;
  int g = batch[wid];
  atomicAdd(&pooled[(size_t)g * H + lane], h[(size_t)wid * H + lane]);
  atomicAdd(&pooled[(size_t)g * H + 64 + lane], h[(size_t)wid * H + 64 + lane]);
  if (lane == 0) atomicAdd(&gcnt[g], 1.0f);
}

// ---------------- final: sigmoid(pooled/cnt @ lin_W + lin_b) ----------------
__global__ __launch_bounds__(256) void k_out(const float* __restrict__ pooled,
    const float* __restrict__ gcnt, const float* __restrict__ lw,
    const float* __restrict__ lb, float* __restrict__ out, int G) {
  int wid = (blockIdx.x * blockDim.x + threadIdx.x) >> 6;
  int lane = threadIdx.x & 63;
  if (wid >= G) return;
  float inv = 1.f / fmaxf(gcnt[wid], 1.f);
  float s = pooled[(size_t)wid * H + lane] * inv * lw[lane]
          + pooled[(size_t)wid * H + 64 + lane] * inv * lw[64 + lane];
#pragma unroll
  for (int off = 32; off > 0; off >>= 1) s += __shfl_down(s, off, 64);
  if (lane == 0) out[wid] = 1.f / (1.f + expf(-(s + lb[0])));
}

extern "C" void kernel_launch(void* const* d_in, const int* in_sizes, int n_in,
                              void* d_out, int out_size, void* d_ws, size_t ws_size,
                              hipStream_t stream) {
  const int* x      = (const int*)d_in[0];
  const int* ei     = (const int*)d_in[1];
  const int* batch  = (const int*)d_in[2];
  const float* emb  = (const float*)d_in[3];
  const float* convW = (const float*)d_in[4];
  const float* convB = (const float*)d_in[5];
  const float* gamma = (const float*)d_in[6];
  const float* beta  = (const float*)d_in[7];
  const float* lw    = (const float*)d_in[8];
  const float* lb    = (const float*)d_in[9];
  float* out = (float*)d_out;

  const int N = in_sizes[2];
  const int E = in_sizes[1] / 2;
  const int G = out_size;
  const int MAXV = in_sizes[3] / (FEAT * H);
  const int L = in_sizes[4] / (H * H);
  const int Npad = (N + 127) & ~127;

  const int* srcp = ei;
  const int* dstp = ei + E;

  char* p = (char*)d_ws;
  auto alloc = [&](size_t bytes) { char* r = p; p += (bytes + 255) & ~255ull; return r; };
  float* h    = (float*)alloc((size_t)Npad * H * 4);
  uint*  ms   = (uint*)alloc((size_t)Npad * 64 * 4);   // bf16x2 packed, pre-scaled
  float* a    = (float*)alloc((size_t)Npad * H * 4);
  float* dinv = (float*)alloc((size_t)N * 4);
  int* row_ptr = (int*)alloc((size_t)(N + 1) * 4);
  int* col     = (int*)alloc((size_t)E * 4);
  int* incl    = (int*)alloc((size_t)N * 4);
  int* bsum    = (int*)alloc(256 * 4);
  char* z0 = p;
  int* counts   = (int*)alloc((size_t)N * 4);
  int* cursor   = (int*)alloc((size_t)N * 4);
  float* bn_sum = (float*)alloc((size_t)L * H * 4);
  float* bn_sq  = (float*)alloc((size_t)L * H * 4);
  float* pooled = (float*)alloc((size_t)G * H * 4);
  float* gcnt   = (float*)alloc((size_t)G * 4);
  size_t zbytes = (size_t)(p - z0);

  hipMemsetAsync(z0, 0, zbytes, stream);

  const int nb = (N + 255) / 256;

  // graph prep
  k_atom<<<Npad / 4, 256, 0, stream>>>(x, emb, h, N, Npad, MAXV);
  k_count<<<(E + 255) / 256, 256, 0, stream>>>(dstp, counts, E);
  k_dinv<<<(N + 255) / 256, 256, 0, stream>>>(counts, dinv, N);
  k_scan1<<<nb, 256, 0, stream>>>(counts, incl, bsum, N);
  k_scan2<<<1, 256, 0, stream>>>(bsum, nb);
  k_scan3<<<nb, 256, 0, stream>>>(incl, bsum, row_ptr, N);
  k_fill<<<(E + 255) / 256, 256, 0, stream>>>(srcp, dstp, row_ptr, cursor, col, E);

  // layers
  for (int l = 0; l < L; ++l) {
    k_gemm<<<Npad / 128, 256, 0, stream>>>(h, convW + (size_t)l * H * H, ms, dinv, N);
    k_agg<<<2048, 256, 0, stream>>>(ms, row_ptr, col, dinv, convB + (size_t)l * H,
                                    a, bn_sum + (size_t)l * H, bn_sq + (size_t)l * H, N);
    k_bn<<<(N * 32 + 255) / 256, 256, 0, stream>>>(a, h, bn_sum + (size_t)l * H,
                                                   bn_sq + (size_t)l * H,
                                                   gamma + (size_t)l * H,
                                                   beta + (size_t)l * H, N);
  }

  // readout
  k_pool<<<(N + 3) / 4, 256, 0, stream>>>(h, batch, pooled, gcnt, N);
  k_out<<<(G + 3) / 4, 256, 0, stream>>>(pooled, gcnt, lw, lb, out, G);
}

// Round 4
// 583.147 us; speedup vs baseline: 1.6816x; 1.1548x over previous
//
#include <hip/hip_runtime.h>
#include <hip/hip_bf16.h>
#include <math.h>

#define H 128
#define FEAT 9

typedef unsigned int uint;
typedef __attribute__((ext_vector_type(8))) short short8;   // 8 bf16 = 4 VGPR
typedef __attribute__((ext_vector_type(4))) float f32x4;

// round-to-nearest-even f32 -> bf16 (finite inputs)
__device__ inline uint f2bf(float f) {
  uint u = __float_as_uint(f);
  return (u + 0x7FFF + ((u >> 16) & 1)) >> 16;
}
__device__ inline uint pk_bf16(float a, float b) {
  return f2bf(a) | (f2bf(b) << 16);
}
#define BLO(u) __uint_as_float((u) << 16)
#define BHI(u) __uint_as_float((u) & 0xFFFF0000u)

// ---------------- Atom encoder: h[v] = sum_f emb[f, x[v,f], :] ----------------
__global__ __launch_bounds__(256) void k_atom(const int* __restrict__ x,
    const float* __restrict__ emb, float* __restrict__ h,
    int N, int Npad, int maxv) {
  int wid = (blockIdx.x * blockDim.x + threadIdx.x) >> 6;
  int lane = threadIdx.x & 63;
  if (wid >= Npad) return;
  float a0 = 0.f, a1 = 0.f;
  if (wid < N) {
    const int* xr = x + (size_t)wid * FEAT;
#pragma unroll
    for (int f = 0; f < FEAT; ++f) {
      int id = xr[f];
      const float* e = emb + ((size_t)f * maxv + id) * H;
      a0 += e[lane];
      a1 += e[lane + 64];
    }
  }
  h[(size_t)wid * H + lane] = a0;
  h[(size_t)wid * H + 64 + lane] = a1;
}

// ---------------- degree count (by dst) ----------------
__global__ __launch_bounds__(256) void k_count(const int* __restrict__ dst,
    int* __restrict__ counts, int E) {
  int i = blockIdx.x * blockDim.x + threadIdx.x;
  if (i < E) atomicAdd(&counts[dst[i]], 1);
}

__global__ __launch_bounds__(256) void k_dinv(const int* __restrict__ counts,
    float* __restrict__ dinv, int N) {
  int i = blockIdx.x * blockDim.x + threadIdx.x;
  if (i < N) dinv[i] = rsqrtf((float)(counts[i] + 1));
}

// ---------------- hierarchical scan ----------------
__global__ __launch_bounds__(256) void k_scan1(const int* __restrict__ counts,
    int* __restrict__ incl, int* __restrict__ bsum, int n) {
  __shared__ int ws[4];
  int t = threadIdx.x;
  int i = blockIdx.x * 256 + t;
  int lane = t & 63, w = t >> 6;
  int v = (i < n) ? counts[i] : 0;
  int s = v;
#pragma unroll
  for (int off = 1; off < 64; off <<= 1) {
    int u = __shfl_up(s, off, 64);
    if (lane >= off) s += u;
  }
  if (lane == 63) ws[w] = s;
  __syncthreads();
  if (t == 0) {
    int acc = 0;
#pragma unroll
    for (int j = 0; j < 4; ++j) { int tmp = ws[j]; ws[j] = acc; acc += tmp; }
  }
  __syncthreads();
  s += ws[w];
  if (i < n) incl[i] = s;
  if (t == 255) bsum[blockIdx.x] = s;
}

__global__ __launch_bounds__(256) void k_scan2(int* __restrict__ bsum, int nb) {
  __shared__ int ws[4];
  int t = threadIdx.x, lane = t & 63, w = t >> 6;
  int v = (t < nb) ? bsum[t] : 0;
  int s = v;
#pragma unroll
  for (int off = 1; off < 64; off <<= 1) {
    int u = __shfl_up(s, off, 64);
    if (lane >= off) s += u;
  }
  if (lane == 63) ws[w] = s;
  __syncthreads();
  if (t == 0) {
    int acc = 0;
#pragma unroll
    for (int j = 0; j < 4; ++j) { int tmp = ws[j]; ws[j] = acc; acc += tmp; }
  }
  __syncthreads();
  s += ws[w];
  if (t < nb) bsum[t] = s - v;   // exclusive
}

__global__ __launch_bounds__(256) void k_scan3(const int* __restrict__ incl,
    const int* __restrict__ boff, int* __restrict__ row_ptr, int n) {
  int i = blockIdx.x * 256 + threadIdx.x;
  if (i < n) row_ptr[i + 1] = incl[i] + boff[i >> 8];
  if (i == 0) row_ptr[0] = 0;
}

// ---------------- CSR fill ----------------
__global__ __launch_bounds__(256) void k_fill(const int* __restrict__ src,
    const int* __restrict__ dst, const int* __restrict__ row_ptr,
    int* __restrict__ cursor, int* __restrict__ col, int E) {
  int i = blockIdx.x * blockDim.x + threadIdx.x;
  if (i < E) {
    int d = dst[i];
    int pos = atomicAdd(&cursor[d], 1);
    col[row_ptr[d] + pos] = src[i];
  }
}

// ---------------- W transpose + bf16: wt[l][n][k] packed pairs ----------------
__global__ __launch_bounds__(256) void k_wt(const float* __restrict__ W,
    uint* __restrict__ wt, int total) {   // total = L*128*64
  int idx = blockIdx.x * 256 + threadIdx.x;
  if (idx >= total) return;
  int l = idx >> 13;
  int rem = idx & 8191;
  int n = rem >> 6;
  int k2 = rem & 63;
  const float* w = W + (size_t)l * H * H;
  float x0 = w[(size_t)(2 * k2) * H + n];
  float x1 = w[(size_t)(2 * k2 + 1) * H + n];
  wt[idx] = pk_bf16(x0, x1);
}

// ---------------- BN fold: sc = gamma*rsqrt(var+eps), bb = beta - mean*sc ----
__global__ void k_bnparm(const float* __restrict__ bn_sum,
    const float* __restrict__ bn_sq, const float* __restrict__ gamma,
    const float* __restrict__ beta, float* __restrict__ sc,
    float* __restrict__ bb, float invN) {
  int c = threadIdx.x;   // 128
  float mean = bn_sum[c] * invN;
  float var = bn_sq[c] * invN - mean * mean;
  float s = gamma[c] * rsqrtf(var + 1e-5f);
  sc[c] = s;
  bb[c] = beta[c] - mean * s;
}

// ---------------- MFMA GEMM: ms = bf16(dinv * (A' @ W)) ----------------
// A' = FUSED ? (relu(sc*a+bb)+hold, also written to hnew) : A.
// 128x128 tile, 4 waves (2x2) of 64x64, bf16 16x16x32 MFMA, XOR-swizzled LDS.
template <int FUSED>
__global__ __launch_bounds__(256) void k_gemm_mfma(
    const float* __restrict__ A, const float* __restrict__ hold,
    float* __restrict__ hnew, const float* __restrict__ sc,
    const float* __restrict__ bb, const uint* __restrict__ wt,
    uint* __restrict__ ms, const float* __restrict__ dinv, int N) {
  __shared__ uint4 smem4[4096];          // 64 KB: sA [0,32K), sB [32K,64K)
  char* smemc = (char*)smem4;
  int t = threadIdx.x;
  int row0 = blockIdx.x * 128;

  // ---- stage A (fp32 -> bf16, fused BN+relu+residual), swizzled ----
#pragma unroll
  for (int it = 0; it < 16; ++it) {
    int i = t + it * 256;                 // float4 slots over [128][32]
    int r = i >> 5;
    int c4 = (i & 31) << 2;
    float4 av = *(const float4*)(A + (size_t)(row0 + r) * H + c4);
    float4 hv;
    if (FUSED) {
      float4 ho = *(const float4*)(hold + (size_t)(row0 + r) * H + c4);
      float4 s4 = *(const float4*)(sc + c4);
      float4 b4 = *(const float4*)(bb + c4);
      hv.x = fmaxf(s4.x * av.x + b4.x, 0.f) + ho.x;
      hv.y = fmaxf(s4.y * av.y + b4.y, 0.f) + ho.y;
      hv.z = fmaxf(s4.z * av.z + b4.z, 0.f) + ho.z;
      hv.w = fmaxf(s4.w * av.w + b4.w, 0.f) + ho.w;
      *(float4*)(hnew + (size_t)(row0 + r) * H + c4) = hv;
    } else {
      hv = av;
    }
    uint2 w2 = { pk_bf16(hv.x, hv.y), pk_bf16(hv.z, hv.w) };
    int byte = r * 256 + ((c4 * 2) ^ ((r & 7) << 4));
    *(uint2*)(smemc + byte) = w2;
  }
  // ---- stage B: wt bf16 [n][k], swizzled ----
#pragma unroll
  for (int it = 0; it < 8; ++it) {
    int i = t + it * 256;                 // uint4 slots over [128][16]
    int n = i >> 4;
    int k16 = i & 15;
    int byte = 32768 + n * 256 + ((k16 * 16) ^ ((n & 7) << 4));
    *(uint4*)(smemc + byte) = ((const uint4*)wt)[i];
  }
  __syncthreads();

  int wid = t >> 6, l = t & 63;
  int wm = wid >> 1, wn = wid & 1;
  int lr = l & 15, lg = l >> 4;           // frag row/col, k-group

  f32x4 acc[4][4];
#pragma unroll
  for (int mt = 0; mt < 4; ++mt)
#pragma unroll
    for (int nt = 0; nt < 4; ++nt) acc[mt][nt] = (f32x4)0.f;

#pragma unroll
  for (int kk = 0; kk < 4; ++kk) {
    int kbyte = kk * 64 + lg * 16;
    short8 af[4], bf[4];
#pragma unroll
    for (int mt = 0; mt < 4; ++mt) {
      int r = wm * 64 + mt * 16 + lr;
      af[mt] = *(const short8*)(smemc + r * 256 + (kbyte ^ ((r & 7) << 4)));
    }
#pragma unroll
    for (int nt = 0; nt < 4; ++nt) {
      int n = wn * 64 + nt * 16 + lr;
      bf[nt] = *(const short8*)(smemc + 32768 + n * 256 + (kbyte ^ ((n & 7) << 4)));
    }
#pragma unroll
    for (int mt = 0; mt < 4; ++mt)
#pragma unroll
      for (int nt = 0; nt < 4; ++nt)
        acc[mt][nt] = __builtin_amdgcn_mfma_f32_16x16x32_bf16(
            af[mt], bf[nt], acc[mt][nt], 0, 0, 0);
  }
  __syncthreads();   // all LDS reads done; sA space becomes sC

  // ---- epilogue: scale by dinv, bf16, bounce through LDS, coalesced out ----
  float dr[4][4];
#pragma unroll
  for (int mt = 0; mt < 4; ++mt)
#pragma unroll
    for (int j = 0; j < 4; ++j) {
      int grow = row0 + wm * 64 + mt * 16 + lg * 4 + j;
      dr[mt][j] = (grow < N) ? dinv[grow] : 0.f;
    }
#pragma unroll
  for (int mt = 0; mt < 4; ++mt)
#pragma unroll
    for (int nt = 0; nt < 4; ++nt)
#pragma unroll
      for (int j = 0; j < 4; ++j) {
        int lrow = wm * 64 + mt * 16 + lg * 4 + j;
        int lcol = wn * 64 + nt * 16 + lr;
        float val = acc[mt][nt][j] * dr[mt][j];
        *(short*)(smemc + lrow * 256 + lcol * 2) = (short)f2bf(val);
      }
  __syncthreads();
#pragma unroll
  for (int it = 0; it < 8; ++it) {
    int i = t + it * 256;                 // uint4 slots over [128][16]
    int r = i >> 4;
    int c16 = i & 15;
    uint4 v = *(const uint4*)(smemc + r * 256 + c16 * 16);
    ((uint4*)ms)[(size_t)(row0 + r) * 16 + c16] = v;
  }
}

// ---------------- aggregate: a = relu(dinv_v * sum(ms) + b), BN stats ----------------
__global__ __launch_bounds__(256) void k_agg(const uint* __restrict__ ms,
    const int* __restrict__ row_ptr, const int* __restrict__ col,
    const float* __restrict__ dinv, const float* __restrict__ bias,
    float* __restrict__ a, float* __restrict__ bn_sum, float* __restrict__ bn_sq,
    int N) {
  __shared__ float s_sum[128], s_sq[128];
  for (int i = threadIdx.x; i < 128; i += 256) { s_sum[i] = 0.f; s_sq[i] = 0.f; }
  __syncthreads();
  int lane = threadIdx.x & 63;
  int wid = (blockIdx.x * 256 + threadIdx.x) >> 6;
  int nw = (gridDim.x * 256) >> 6;
  float b0 = bias[2 * lane], b1 = bias[2 * lane + 1];
  float lsum0 = 0.f, lsq0 = 0.f, lsum1 = 0.f, lsq1 = 0.f;
  for (int v = wid; v < N; v += nw) {
    int s0 = row_ptr[v], s1 = row_ptr[v + 1];
    float dv = dinv[v];
    uint sv = ms[(size_t)v * 64 + lane];
    float acc0 = BLO(sv), acc1 = BHI(sv);
    int s = s0;
    for (; s + 8 <= s1; s += 8) {
      int u0 = col[s], u1 = col[s + 1], u2 = col[s + 2], u3 = col[s + 3];
      int u4 = col[s + 4], u5 = col[s + 5], u6 = col[s + 6], u7 = col[s + 7];
      uint w0 = ms[(size_t)u0 * 64 + lane];
      uint w1 = ms[(size_t)u1 * 64 + lane];
      uint w2 = ms[(size_t)u2 * 64 + lane];
      uint w3 = ms[(size_t)u3 * 64 + lane];
      uint w4 = ms[(size_t)u4 * 64 + lane];
      uint w5 = ms[(size_t)u5 * 64 + lane];
      uint w6 = ms[(size_t)u6 * 64 + lane];
      uint w7 = ms[(size_t)u7 * 64 + lane];
      acc0 += BLO(w0) + BLO(w1) + BLO(w2) + BLO(w3)
            + BLO(w4) + BLO(w5) + BLO(w6) + BLO(w7);
      acc1 += BHI(w0) + BHI(w1) + BHI(w2) + BHI(w3)
            + BHI(w4) + BHI(w5) + BHI(w6) + BHI(w7);
    }
    for (; s + 4 <= s1; s += 4) {
      int u0 = col[s], u1 = col[s + 1], u2 = col[s + 2], u3 = col[s + 3];
      uint w0 = ms[(size_t)u0 * 64 + lane];
      uint w1 = ms[(size_t)u1 * 64 + lane];
      uint w2 = ms[(size_t)u2 * 64 + lane];
      uint w3 = ms[(size_t)u3 * 64 + lane];
      acc0 += BLO(w0) + BLO(w1) + BLO(w2) + BLO(w3);
      acc1 += BHI(w0) + BHI(w1) + BHI(w2) + BHI(w3);
    }
    for (; s < s1; ++s) {
      uint w = ms[(size_t)col[s] * 64 + lane];
      acc0 += BLO(w);
      acc1 += BHI(w);
    }
    float a0 = fmaxf(dv * acc0 + b0, 0.f);
    float a1 = fmaxf(dv * acc1 + b1, 0.f);
    float2 av = {a0, a1};
    *(float2*)(a + (size_t)v * H + 2 * lane) = av;
    lsum0 += a0; lsq0 += a0 * a0;
    lsum1 += a1; lsq1 += a1 * a1;
  }
  atomicAdd(&s_sum[2 * lane], lsum0);
  atomicAdd(&s_sum[2 * lane + 1], lsum1);
  atomicAdd(&s_sq[2 * lane], lsq0);
  atomicAdd(&s_sq[2 * lane + 1], lsq1);
  __syncthreads();
  for (int i = threadIdx.x; i < 128; i += 256) {
    atomicAdd(&bn_sum[i], s_sum[i]);
    atomicAdd(&bn_sq[i], s_sq[i]);
  }
}

// ---------------- mean-pool readout with fused final BN ----------------
__global__ __launch_bounds__(256) void k_pool(const float* __restrict__ a,
    const float* __restrict__ hold, const float* __restrict__ sc,
    const float* __restrict__ bb, const int* __restrict__ batch,
    float* __restrict__ pooled, float* __restrict__ gcnt, int N) {
  int wid = (blockIdx.x * blockDim.x + threadIdx.x) >> 6;
  int lane = threadIdx.x & 63;
  if (wid >= N) return;
  int g = batch[wid];
  float2 av = *(const float2*)(a + (size_t)wid * H + 2 * lane);
  float2 hv = *(const float2*)(hold + (size_t)wid * H + 2 * lane);
  float2 s2 = *(const float2*)(sc + 2 * lane);
  float2 b2 = *(const float2*)(bb + 2 * lane);
  float h0 = fmaxf(s2.x * av.x + b2.x, 0.f) + hv.x;
  float h1 = fmaxf(s2.y * av.y + b2.y, 0.f) + hv.y;
  atomicAdd(&pooled[(size_t)g * H + 2 * lane], h0);
  atomicAdd(&pooled[(size_t)g * H + 2 * lane + 1], h1);
  if (lane == 0) atomicAdd(&gcnt[g], 1.0f);
}

// ---------------- final: sigmoid(pooled/cnt @ lin_W + lin_b) ----------------
__global__ __launch_bounds__(256) void k_out(const float* __restrict__ pooled,
    const float* __restrict__ gcnt, const float* __restrict__ lw,
    const float* __restrict__ lb, float* __restrict__ out, int G) {
  int wid = (blockIdx.x * blockDim.x + threadIdx.x) >> 6;
  int lane = threadIdx.x & 63;
  if (wid >= G) return;
  float inv = 1.f / fmaxf(gcnt[wid], 1.f);
  float s = pooled[(size_t)wid * H + lane] * inv * lw[lane]
          + pooled[(size_t)wid * H + 64 + lane] * inv * lw[64 + lane];
#pragma unroll
  for (int off = 32; off > 0; off >>= 1) s += __shfl_down(s, off, 64);
  if (lane == 0) out[wid] = 1.f / (1.f + expf(-(s + lb[0])));
}

extern "C" void kernel_launch(void* const* d_in, const int* in_sizes, int n_in,
                              void* d_out, int out_size, void* d_ws, size_t ws_size,
                              hipStream_t stream) {
  const int* x      = (const int*)d_in[0];
  const int* ei     = (const int*)d_in[1];
  const int* batch  = (const int*)d_in[2];
  const float* emb  = (const float*)d_in[3];
  const float* convW = (const float*)d_in[4];
  const float* convB = (const float*)d_in[5];
  const float* gamma = (const float*)d_in[6];
  const float* beta  = (const float*)d_in[7];
  const float* lw    = (const float*)d_in[8];
  const float* lb    = (const float*)d_in[9];
  float* out = (float*)d_out;

  const int N = in_sizes[2];
  const int E = in_sizes[1] / 2;
  const int G = out_size;
  const int MAXV = in_sizes[3] / (FEAT * H);
  const int L = in_sizes[4] / (H * H);
  const int Npad = (N + 127) & ~127;

  const int* srcp = ei;
  const int* dstp = ei + E;

  char* p = (char*)d_ws;
  auto alloc = [&](size_t bytes) { char* r = p; p += (bytes + 255) & ~255ull; return r; };
  float* h    = (float*)alloc((size_t)Npad * H * 4);
  uint*  ms   = (uint*)alloc((size_t)Npad * 64 * 4);   // bf16x2 packed, pre-scaled
  float* a    = (float*)alloc((size_t)Npad * H * 4);
  float* dinv = (float*)alloc((size_t)N * 4);
  int* row_ptr = (int*)alloc((size_t)(N + 1) * 4);
  int* col     = (int*)alloc((size_t)E * 4);
  int* incl    = (int*)alloc((size_t)N * 4);
  int* bsum    = (int*)alloc(256 * 4);
  uint* wt     = (uint*)alloc((size_t)L * H * 64 * 4); // WT bf16 [l][n][k/2]
  float* scb   = (float*)alloc((size_t)L * H * 4);
  float* bbb   = (float*)alloc((size_t)L * H * 4);
  char* z0 = p;
  int* counts   = (int*)alloc((size_t)N * 4);
  int* cursor   = (int*)alloc((size_t)N * 4);
  float* bn_sum = (float*)alloc((size_t)L * H * 4);
  float* bn_sq  = (float*)alloc((size_t)L * H * 4);
  float* pooled = (float*)alloc((size_t)G * H * 4);
  float* gcnt   = (float*)alloc((size_t)G * 4);
  size_t zbytes = (size_t)(p - z0);

  hipMemsetAsync(z0, 0, zbytes, stream);

  const int nb = (N + 255) / 256;
  const float invN = 1.0f / (float)N;

  // graph prep
  k_atom<<<Npad / 4, 256, 0, stream>>>(x, emb, h, N, Npad, MAXV);
  k_count<<<(E + 255) / 256, 256, 0, stream>>>(dstp, counts, E);
  k_dinv<<<(N + 255) / 256, 256, 0, stream>>>(counts, dinv, N);
  k_scan1<<<nb, 256, 0, stream>>>(counts, incl, bsum, N);
  k_scan2<<<1, 256, 0, stream>>>(bsum, nb);
  k_scan3<<<nb, 256, 0, stream>>>(incl, bsum, row_ptr, N);
  k_fill<<<(E + 255) / 256, 256, 0, stream>>>(srcp, dstp, row_ptr, cursor, col, E);
  k_wt<<<(L * H * 64 + 255) / 256, 256, 0, stream>>>(convW, wt, L * H * 64);

  // layers
  for (int l = 0; l < L; ++l) {
    if (l == 0) {
      k_gemm_mfma<0><<<Npad / 128, 256, 0, stream>>>(
          h, nullptr, nullptr, nullptr, nullptr,
          wt, ms, dinv, N);
    } else {
      k_gemm_mfma<1><<<Npad / 128, 256, 0, stream>>>(
          a, h, h, scb + (size_t)(l - 1) * H, bbb + (size_t)(l - 1) * H,
          wt + (size_t)l * H * 64, ms, dinv, N);
    }
    k_agg<<<2048, 256, 0, stream>>>(ms, row_ptr, col, dinv, convB + (size_t)l * H,
                                    a, bn_sum + (size_t)l * H, bn_sq + (size_t)l * H, N);
    k_bnparm<<<1, 128, 0, stream>>>(bn_sum + (size_t)l * H, bn_sq + (size_t)l * H,
                                    gamma + (size_t)l * H, beta + (size_t)l * H,
                                    scb + (size_t)l * H, bbb + (size_t)l * H, invN);
  }

  // readout (fused final BN)
  k_pool<<<(N + 3) / 4, 256, 0, stream>>>(a, h, scb + (size_t)(L - 1) * H,
                                          bbb + (size_t)(L - 1) * H, batch,
                                          pooled, gcnt, N);
  k_out<<<(G + 3) / 4, 256, 0, stream>>>(pooled, gcnt, lw, lb, out, G);
}

// Round 5
// 511.210 us; speedup vs baseline: 1.9182x; 1.1407x over previous
//
#include <hip/hip_runtime.h>
#include <hip/hip_bf16.h>
#include <math.h>

#define H 128
#define FEAT 9

typedef unsigned int uint;
typedef __attribute__((ext_vector_type(8))) short short8;   // 8 bf16 = 4 VGPR
typedef __attribute__((ext_vector_type(4))) float f32x4;

// round-to-nearest-even f32 -> bf16 (finite inputs)
__device__ inline uint f2bf(float f) {
  uint u = __float_as_uint(f);
  return (u + 0x7FFF + ((u >> 16) & 1)) >> 16;
}
__device__ inline uint pk_bf16(float a, float b) {
  return f2bf(a) | (f2bf(b) << 16);
}
#define BLO(u) __uint_as_float((u) << 16)
#define BHI(u) __uint_as_float((u) & 0xFFFF0000u)

// ---------------- Atom encoder: h[v] = sum_f emb[f, x[v,f], :] ----------------
__global__ __launch_bounds__(256) void k_atom(const int* __restrict__ x,
    const float* __restrict__ emb, float* __restrict__ h,
    int N, int Npad, int maxv) {
  int wid = (blockIdx.x * blockDim.x + threadIdx.x) >> 6;
  int lane = threadIdx.x & 63;
  if (wid >= Npad) return;
  float a0 = 0.f, a1 = 0.f;
  if (wid < N) {
    const int* xr = x + (size_t)wid * FEAT;
#pragma unroll
    for (int f = 0; f < FEAT; ++f) {
      int id = xr[f];
      const float* e = emb + ((size_t)f * maxv + id) * H;
      a0 += e[lane];
      a1 += e[lane + 64];
    }
  }
  h[(size_t)wid * H + lane] = a0;
  h[(size_t)wid * H + 64 + lane] = a1;
}

// ---------------- degree count (by dst) ----------------
__global__ __launch_bounds__(256) void k_count(const int* __restrict__ dst,
    int* __restrict__ counts, int E) {
  int i = blockIdx.x * blockDim.x + threadIdx.x;
  if (i < E) atomicAdd(&counts[dst[i]], 1);
}

__global__ __launch_bounds__(256) void k_dinv(const int* __restrict__ counts,
    float* __restrict__ dinv, int N) {
  int i = blockIdx.x * blockDim.x + threadIdx.x;
  if (i < N) dinv[i] = rsqrtf((float)(counts[i] + 1));
}

// ---------------- hierarchical scan ----------------
__global__ __launch_bounds__(256) void k_scan1(const int* __restrict__ counts,
    int* __restrict__ incl, int* __restrict__ bsum, int n) {
  __shared__ int ws[4];
  int t = threadIdx.x;
  int i = blockIdx.x * 256 + t;
  int lane = t & 63, w = t >> 6;
  int v = (i < n) ? counts[i] : 0;
  int s = v;
#pragma unroll
  for (int off = 1; off < 64; off <<= 1) {
    int u = __shfl_up(s, off, 64);
    if (lane >= off) s += u;
  }
  if (lane == 63) ws[w] = s;
  __syncthreads();
  if (t == 0) {
    int acc = 0;
#pragma unroll
    for (int j = 0; j < 4; ++j) { int tmp = ws[j]; ws[j] = acc; acc += tmp; }
  }
  __syncthreads();
  s += ws[w];
  if (i < n) incl[i] = s;
  if (t == 255) bsum[blockIdx.x] = s;
}

__global__ __launch_bounds__(256) void k_scan2(int* __restrict__ bsum, int nb) {
  __shared__ int ws[4];
  int t = threadIdx.x, lane = t & 63, w = t >> 6;
  int v = (t < nb) ? bsum[t] : 0;
  int s = v;
#pragma unroll
  for (int off = 1; off < 64; off <<= 1) {
    int u = __shfl_up(s, off, 64);
    if (lane >= off) s += u;
  }
  if (lane == 63) ws[w] = s;
  __syncthreads();
  if (t == 0) {
    int acc = 0;
#pragma unroll
    for (int j = 0; j < 4; ++j) { int tmp = ws[j]; ws[j] = acc; acc += tmp; }
  }
  __syncthreads();
  s += ws[w];
  if (t < nb) bsum[t] = s - v;   // exclusive
}

__global__ __launch_bounds__(256) void k_scan3(const int* __restrict__ incl,
    const int* __restrict__ boff, int* __restrict__ row_ptr, int n) {
  int i = blockIdx.x * 256 + threadIdx.x;
  if (i < n) row_ptr[i + 1] = incl[i] + boff[i >> 8];
  if (i == 0) row_ptr[0] = 0;
}

// ---------------- CSR fill ----------------
__global__ __launch_bounds__(256) void k_fill(const int* __restrict__ src,
    const int* __restrict__ dst, const int* __restrict__ row_ptr,
    int* __restrict__ cursor, int* __restrict__ col, int E) {
  int i = blockIdx.x * blockDim.x + threadIdx.x;
  if (i < E) {
    int d = dst[i];
    int pos = atomicAdd(&cursor[d], 1);
    col[row_ptr[d] + pos] = src[i];
  }
}

// ---------------- graph boundaries: gstart[g] = first node with batch >= g ----
__global__ __launch_bounds__(256) void k_bound(const int* __restrict__ batch,
    int* __restrict__ gstart, int N, int G) {
  int i = blockIdx.x * 256 + threadIdx.x;
  if (i > N) return;
  int lo = (i == 0) ? 0 : batch[i - 1] + 1;
  int hi = (i == N) ? G : batch[i];
  for (int g = lo; g <= hi; ++g) gstart[g] = i;
}

// ---------------- W transpose + bf16: wt[l][n][k] packed pairs ----------------
__global__ __launch_bounds__(256) void k_wt(const float* __restrict__ W,
    uint* __restrict__ wt, int total) {   // total = L*128*64
  int idx = blockIdx.x * 256 + threadIdx.x;
  if (idx >= total) return;
  int l = idx >> 13;
  int rem = idx & 8191;
  int n = rem >> 6;
  int k2 = rem & 63;
  const float* w = W + (size_t)l * H * H;
  float x0 = w[(size_t)(2 * k2) * H + n];
  float x1 = w[(size_t)(2 * k2 + 1) * H + n];
  wt[idx] = pk_bf16(x0, x1);
}

// ---------------- BN fold: sc = gamma*rsqrt(var+eps), bb = beta - mean*sc ----
__global__ void k_bnparm(const float* __restrict__ bn_sum,
    const float* __restrict__ bn_sq, const float* __restrict__ gamma,
    const float* __restrict__ beta, float* __restrict__ sc,
    float* __restrict__ bb, float invN) {
  int c = threadIdx.x;   // 128
  float mean = bn_sum[c] * invN;
  float var = bn_sq[c] * invN - mean * mean;
  float s = gamma[c] * rsqrtf(var + 1e-5f);
  sc[c] = s;
  bb[c] = beta[c] - mean * s;
}

// ---------------- MFMA GEMM: ms = bf16(dinv * (A' @ W)) ----------------
// A' = FUSED ? (relu(sc*a_bf16+bb)+hold, also written to hnew) : Af (fp32).
// 128x128 tile, 4 waves (2x2) of 64x64, bf16 16x16x32 MFMA, XOR-swizzled LDS.
template <int FUSED>
__global__ __launch_bounds__(256) void k_gemm_mfma(
    const float* __restrict__ Af, const uint* __restrict__ Ap,
    const float* __restrict__ hold, float* __restrict__ hnew,
    const float* __restrict__ sc, const float* __restrict__ bb,
    const uint* __restrict__ wt, uint* __restrict__ ms,
    const float* __restrict__ dinv, int N) {
  __shared__ uint4 smem4[4096];          // 64 KB: sA [0,32K), sB [32K,64K)
  char* smemc = (char*)smem4;
  int t = threadIdx.x;
  int row0 = blockIdx.x * 128;

  // ---- stage A, swizzled (16B granularity) ----
#pragma unroll
  for (int it = 0; it < 8; ++it) {
    int i = t + it * 256;                 // uint4 slots over [128][16]
    int r = i >> 4;
    int c16 = i & 15;
    int c0 = c16 * 8;
    uint4 w4;
    if (FUSED) {
      uint4 av = *(const uint4*)(Ap + (size_t)(row0 + r) * 64 + c16 * 4);
      const float* hrow = hold + (size_t)(row0 + r) * H + c0;
      float4 ho0 = *(const float4*)(hrow);
      float4 ho1 = *(const float4*)(hrow + 4);
      float4 s0 = *(const float4*)(sc + c0), s1 = *(const float4*)(sc + c0 + 4);
      float4 b0 = *(const float4*)(bb + c0), b1 = *(const float4*)(bb + c0 + 4);
      float h0 = fmaxf(s0.x * BLO(av.x) + b0.x, 0.f) + ho0.x;
      float h1 = fmaxf(s0.y * BHI(av.x) + b0.y, 0.f) + ho0.y;
      float h2 = fmaxf(s0.z * BLO(av.y) + b0.z, 0.f) + ho0.z;
      float h3 = fmaxf(s0.w * BHI(av.y) + b0.w, 0.f) + ho0.w;
      float h4 = fmaxf(s1.x * BLO(av.z) + b1.x, 0.f) + ho1.x;
      float h5 = fmaxf(s1.y * BHI(av.z) + b1.y, 0.f) + ho1.y;
      float h6 = fmaxf(s1.z * BLO(av.w) + b1.z, 0.f) + ho1.z;
      float h7 = fmaxf(s1.w * BHI(av.w) + b1.w, 0.f) + ho1.w;
      float* nrow = hnew + (size_t)(row0 + r) * H + c0;
      float4 o0 = {h0, h1, h2, h3}, o1 = {h4, h5, h6, h7};
      *(float4*)nrow = o0;
      *(float4*)(nrow + 4) = o1;
      w4.x = pk_bf16(h0, h1); w4.y = pk_bf16(h2, h3);
      w4.z = pk_bf16(h4, h5); w4.w = pk_bf16(h6, h7);
    } else {
      const float* arow = Af + (size_t)(row0 + r) * H + c0;
      float4 v0 = *(const float4*)arow;
      float4 v1 = *(const float4*)(arow + 4);
      w4.x = pk_bf16(v0.x, v0.y); w4.y = pk_bf16(v0.z, v0.w);
      w4.z = pk_bf16(v1.x, v1.y); w4.w = pk_bf16(v1.z, v1.w);
    }
    int byte = r * 256 + ((c16 * 16) ^ ((r & 7) << 4));
    *(uint4*)(smemc + byte) = w4;
  }
  // ---- stage B: wt bf16 [n][k], swizzled ----
#pragma unroll
  for (int it = 0; it < 8; ++it) {
    int i = t + it * 256;                 // uint4 slots over [128][16]
    int n = i >> 4;
    int k16 = i & 15;
    int byte = 32768 + n * 256 + ((k16 * 16) ^ ((n & 7) << 4));
    *(uint4*)(smemc + byte) = ((const uint4*)wt)[i];
  }
  __syncthreads();

  int wid = t >> 6, l = t & 63;
  int wm = wid >> 1, wn = wid & 1;
  int lr = l & 15, lg = l >> 4;           // frag row/col, k-group

  f32x4 acc[4][4];
#pragma unroll
  for (int mt = 0; mt < 4; ++mt)
#pragma unroll
    for (int nt = 0; nt < 4; ++nt) acc[mt][nt] = (f32x4)0.f;

#pragma unroll
  for (int kk = 0; kk < 4; ++kk) {
    int kbyte = kk * 64 + lg * 16;
    short8 af[4], bf[4];
#pragma unroll
    for (int mt = 0; mt < 4; ++mt) {
      int r = wm * 64 + mt * 16 + lr;
      af[mt] = *(const short8*)(smemc + r * 256 + (kbyte ^ ((r & 7) << 4)));
    }
#pragma unroll
    for (int nt = 0; nt < 4; ++nt) {
      int n = wn * 64 + nt * 16 + lr;
      bf[nt] = *(const short8*)(smemc + 32768 + n * 256 + (kbyte ^ ((n & 7) << 4)));
    }
#pragma unroll
    for (int mt = 0; mt < 4; ++mt)
#pragma unroll
      for (int nt = 0; nt < 4; ++nt)
        acc[mt][nt] = __builtin_amdgcn_mfma_f32_16x16x32_bf16(
            af[mt], bf[nt], acc[mt][nt], 0, 0, 0);
  }
  __syncthreads();   // all LDS reads done; sA space becomes sC

  // ---- epilogue: scale by dinv, bf16, bounce through LDS, coalesced out ----
  float dr[4][4];
#pragma unroll
  for (int mt = 0; mt < 4; ++mt)
#pragma unroll
    for (int j = 0; j < 4; ++j) {
      int grow = row0 + wm * 64 + mt * 16 + lg * 4 + j;
      dr[mt][j] = (grow < N) ? dinv[grow] : 0.f;
    }
#pragma unroll
  for (int mt = 0; mt < 4; ++mt)
#pragma unroll
    for (int nt = 0; nt < 4; ++nt)
#pragma unroll
      for (int j = 0; j < 4; ++j) {
        int lrow = wm * 64 + mt * 16 + lg * 4 + j;
        int lcol = wn * 64 + nt * 16 + lr;
        float val = acc[mt][nt][j] * dr[mt][j];
        *(short*)(smemc + lrow * 256 + lcol * 2) = (short)f2bf(val);
      }
  __syncthreads();
#pragma unroll
  for (int it = 0; it < 8; ++it) {
    int i = t + it * 256;                 // uint4 slots over [128][16]
    int r = i >> 4;
    int c16 = i & 15;
    uint4 v = *(const uint4*)(smemc + r * 256 + c16 * 16);
    ((uint4*)ms)[(size_t)(row0 + r) * 16 + c16] = v;
  }
}

// ---------------- aggregate: a = bf16(relu(dinv_v*sum(ms)+b)), BN stats -------
__global__ __launch_bounds__(256) void k_agg(const uint* __restrict__ ms,
    const int* __restrict__ row_ptr, const int* __restrict__ col,
    const float* __restrict__ dinv, const float* __restrict__ bias,
    uint* __restrict__ a, float* __restrict__ bn_sum, float* __restrict__ bn_sq,
    int N) {
  __shared__ float s_sum[128], s_sq[128];
  for (int i = threadIdx.x; i < 128; i += 256) { s_sum[i] = 0.f; s_sq[i] = 0.f; }
  __syncthreads();
  int lane = threadIdx.x & 63;
  int wid = (blockIdx.x * 256 + threadIdx.x) >> 6;
  int nw = (gridDim.x * 256) >> 6;
  float b0 = bias[2 * lane], b1 = bias[2 * lane + 1];
  float lsum0 = 0.f, lsq0 = 0.f, lsum1 = 0.f, lsq1 = 0.f;
  for (int v = wid; v < N; v += nw) {
    int s0 = row_ptr[v], s1 = row_ptr[v + 1];
    float dv = dinv[v];
    uint sv = ms[(size_t)v * 64 + lane];
    float acc0 = BLO(sv), acc1 = BHI(sv);
    int s = s0;
    for (; s + 8 <= s1; s += 8) {
      int u0 = col[s], u1 = col[s + 1], u2 = col[s + 2], u3 = col[s + 3];
      int u4 = col[s + 4], u5 = col[s + 5], u6 = col[s + 6], u7 = col[s + 7];
      uint w0 = ms[(size_t)u0 * 64 + lane];
      uint w1 = ms[(size_t)u1 * 64 + lane];
      uint w2 = ms[(size_t)u2 * 64 + lane];
      uint w3 = ms[(size_t)u3 * 64 + lane];
      uint w4 = ms[(size_t)u4 * 64 + lane];
      uint w5 = ms[(size_t)u5 * 64 + lane];
      uint w6 = ms[(size_t)u6 * 64 + lane];
      uint w7 = ms[(size_t)u7 * 64 + lane];
      acc0 += BLO(w0) + BLO(w1) + BLO(w2) + BLO(w3)
            + BLO(w4) + BLO(w5) + BLO(w6) + BLO(w7);
      acc1 += BHI(w0) + BHI(w1) + BHI(w2) + BHI(w3)
            + BHI(w4) + BHI(w5) + BHI(w6) + BHI(w7);
    }
    for (; s + 4 <= s1; s += 4) {
      int u0 = col[s], u1 = col[s + 1], u2 = col[s + 2], u3 = col[s + 3];
      uint w0 = ms[(size_t)u0 * 64 + lane];
      uint w1 = ms[(size_t)u1 * 64 + lane];
      uint w2 = ms[(size_t)u2 * 64 + lane];
      uint w3 = ms[(size_t)u3 * 64 + lane];
      acc0 += BLO(w0) + BLO(w1) + BLO(w2) + BLO(w3);
      acc1 += BHI(w0) + BHI(w1) + BHI(w2) + BHI(w3);
    }
    for (; s < s1; ++s) {
      uint w = ms[(size_t)col[s] * 64 + lane];
      acc0 += BLO(w);
      acc1 += BHI(w);
    }
    float a0 = fmaxf(dv * acc0 + b0, 0.f);
    float a1 = fmaxf(dv * acc1 + b1, 0.f);
    uint w = pk_bf16(a0, a1);
    a[(size_t)v * 64 + lane] = w;
    float r0 = BLO(w), r1 = BHI(w);
    lsum0 += r0; lsq0 += r0 * r0;
    lsum1 += r1; lsq1 += r1 * r1;
  }
  atomicAdd(&s_sum[2 * lane], lsum0);
  atomicAdd(&s_sum[2 * lane + 1], lsum1);
  atomicAdd(&s_sq[2 * lane], lsq0);
  atomicAdd(&s_sq[2 * lane + 1], lsq1);
  __syncthreads();
  for (int i = threadIdx.x; i < 128; i += 256) {
    atomicAdd(&bn_sum[i], s_sum[i]);
    atomicAdd(&bn_sq[i], s_sq[i]);
  }
}

// ------- fused readout: one wave per graph, BN+relu+residual+mean+linear ------
__global__ __launch_bounds__(256) void k_poolout(const uint* __restrict__ a,
    const float* __restrict__ hold, const float* __restrict__ sc,
    const float* __restrict__ bb, const int* __restrict__ gstart,
    const float* __restrict__ lw, const float* __restrict__ lb,
    float* __restrict__ out, int G) {
  int g = (blockIdx.x * 256 + threadIdx.x) >> 6;
  int lane = threadIdx.x & 63;
  if (g >= G) return;
  int s0 = gstart[g], s1 = gstart[g + 1];
  float2 s2 = *(const float2*)(sc + 2 * lane);
  float2 b2 = *(const float2*)(bb + 2 * lane);
  float acc0 = 0.f, acc1 = 0.f;
  for (int v = s0; v < s1; ++v) {
    uint av = a[(size_t)v * 64 + lane];
    float2 hv = *(const float2*)(hold + (size_t)v * H + 2 * lane);
    acc0 += fmaxf(s2.x * BLO(av) + b2.x, 0.f) + hv.x;
    acc1 += fmaxf(s2.y * BHI(av) + b2.y, 0.f) + hv.y;
  }
  float inv = 1.f / fmaxf((float)(s1 - s0), 1.f);
  float2 w2 = *(const float2*)(lw + 2 * lane);
  float s = acc0 * inv * w2.x + acc1 * inv * w2.y;
#pragma unroll
  for (int off = 32; off > 0; off >>= 1) s += __shfl_down(s, off, 64);
  if (lane == 0) out[g] = 1.f / (1.f + expf(-(s + lb[0])));
}

extern "C" void kernel_launch(void* const* d_in, const int* in_sizes, int n_in,
                              void* d_out, int out_size, void* d_ws, size_t ws_size,
                              hipStream_t stream) {
  const int* x      = (const int*)d_in[0];
  const int* ei     = (const int*)d_in[1];
  const int* batch  = (const int*)d_in[2];
  const float* emb  = (const float*)d_in[3];
  const float* convW = (const float*)d_in[4];
  const float* convB = (const float*)d_in[5];
  const float* gamma = (const float*)d_in[6];
  const float* beta  = (const float*)d_in[7];
  const float* lw    = (const float*)d_in[8];
  const float* lb    = (const float*)d_in[9];
  float* out = (float*)d_out;

  const int N = in_sizes[2];
  const int E = in_sizes[1] / 2;
  const int G = out_size;
  const int MAXV = in_sizes[3] / (FEAT * H);
  const int L = in_sizes[4] / (H * H);
  const int Npad = (N + 127) & ~127;

  const int* srcp = ei;
  const int* dstp = ei + E;

  char* p = (char*)d_ws;
  auto alloc = [&](size_t bytes) { char* r = p; p += (bytes + 255) & ~255ull; return r; };
  float* h    = (float*)alloc((size_t)Npad * H * 4);
  uint*  ms   = (uint*)alloc((size_t)Npad * 64 * 4);   // bf16x2 packed, pre-scaled
  uint*  a    = (uint*)alloc((size_t)Npad * 64 * 4);   // bf16x2 packed activations
  float* dinv = (float*)alloc((size_t)N * 4);
  int* row_ptr = (int*)alloc((size_t)(N + 1) * 4);
  int* col     = (int*)alloc((size_t)E * 4);
  int* incl    = (int*)alloc((size_t)N * 4);
  int* bsum    = (int*)alloc(256 * 4);
  uint* wt     = (uint*)alloc((size_t)L * H * 64 * 4); // WT bf16 [l][n][k/2]
  float* scb   = (float*)alloc((size_t)L * H * 4);
  float* bbb   = (float*)alloc((size_t)L * H * 4);
  int* gstart  = (int*)alloc((size_t)(G + 1) * 4);
  char* z0 = p;
  int* counts   = (int*)alloc((size_t)N * 4);
  int* cursor   = (int*)alloc((size_t)N * 4);
  float* bn_sum = (float*)alloc((size_t)L * H * 4);
  float* bn_sq  = (float*)alloc((size_t)L * H * 4);
  size_t zbytes = (size_t)(p - z0);

  hipMemsetAsync(z0, 0, zbytes, stream);

  const int nb = (N + 255) / 256;
  const float invN = 1.0f / (float)N;

  // graph prep
  k_atom<<<Npad / 4, 256, 0, stream>>>(x, emb, h, N, Npad, MAXV);
  k_count<<<(E + 255) / 256, 256, 0, stream>>>(dstp, counts, E);
  k_dinv<<<(N + 255) / 256, 256, 0, stream>>>(counts, dinv, N);
  k_scan1<<<nb, 256, 0, stream>>>(counts, incl, bsum, N);
  k_scan2<<<1, 256, 0, stream>>>(bsum, nb);
  k_scan3<<<nb, 256, 0, stream>>>(incl, bsum, row_ptr, N);
  k_fill<<<(E + 255) / 256, 256, 0, stream>>>(srcp, dstp, row_ptr, cursor, col, E);
  k_bound<<<(N + 256) / 256, 256, 0, stream>>>(batch, gstart, N, G);
  k_wt<<<(L * H * 64 + 255) / 256, 256, 0, stream>>>(convW, wt, L * H * 64);

  // layers
  for (int l = 0; l < L; ++l) {
    if (l == 0) {
      k_gemm_mfma<0><<<Npad / 128, 256, 0, stream>>>(
          h, nullptr, nullptr, nullptr, nullptr, nullptr,
          wt, ms, dinv, N);
    } else {
      k_gemm_mfma<1><<<Npad / 128, 256, 0, stream>>>(
          nullptr, a, h, h, scb + (size_t)(l - 1) * H, bbb + (size_t)(l - 1) * H,
          wt + (size_t)l * H * 64, ms, dinv, N);
    }
    k_agg<<<2048, 256, 0, stream>>>(ms, row_ptr, col, dinv, convB + (size_t)l * H,
                                    a, bn_sum + (size_t)l * H, bn_sq + (size_t)l * H, N);
    k_bnparm<<<1, 128, 0, stream>>>(bn_sum + (size_t)l * H, bn_sq + (size_t)l * H,
                                    gamma + (size_t)l * H, beta + (size_t)l * H,
                                    scb + (size_t)l * H, bbb + (size_t)l * H, invN);
  }

  // fused readout (final BN + relu + residual + mean-pool + linear + sigmoid)
  k_poolout<<<(G + 3) / 4, 256, 0, stream>>>(a, h, scb + (size_t)(L - 1) * H,
                                             bbb + (size_t)(L - 1) * H, gstart,
                                             lw, lb, out, G);
}

// Round 6
// 493.349 us; speedup vs baseline: 1.9877x; 1.0362x over previous
//
#include <hip/hip_runtime.h>
#include <hip/hip_bf16.h>
#include <math.h>

#define H 128
#define FEAT 9

typedef unsigned int uint;
typedef __attribute__((ext_vector_type(8))) short short8;   // 8 bf16 = 4 VGPR
typedef __attribute__((ext_vector_type(4))) float f32x4;

// round-to-nearest-even f32 -> bf16 (finite inputs)
__device__ inline uint f2bf(float f) {
  uint u = __float_as_uint(f);
  return (u + 0x7FFF + ((u >> 16) & 1)) >> 16;
}
__device__ inline uint pk_bf16(float a, float b) {
  return f2bf(a) | (f2bf(b) << 16);
}
#define BLO(u) __uint_as_float((u) << 16)
#define BHI(u) __uint_as_float((u) & 0xFFFF0000u)

// ---------------- Atom encoder: h[v] = sum_f emb[f, x[v,f], :] ----------------
__global__ __launch_bounds__(256) void k_atom(const int* __restrict__ x,
    const float* __restrict__ emb, float* __restrict__ h,
    int N, int Npad, int maxv) {
  int wid = (blockIdx.x * blockDim.x + threadIdx.x) >> 6;
  int lane = threadIdx.x & 63;
  if (wid >= Npad) return;
  float a0 = 0.f, a1 = 0.f;
  if (wid < N) {
    const int* xr = x + (size_t)wid * FEAT;
#pragma unroll
    for (int f = 0; f < FEAT; ++f) {
      int id = xr[f];
      const float* e = emb + ((size_t)f * maxv + id) * H;
      a0 += e[lane];
      a1 += e[lane + 64];
    }
  }
  h[(size_t)wid * H + lane] = a0;
  h[(size_t)wid * H + 64 + lane] = a1;
}

// ---------------- degree count (by dst) ----------------
__global__ __launch_bounds__(256) void k_count(const int* __restrict__ dst,
    int* __restrict__ counts, int E) {
  int i = blockIdx.x * blockDim.x + threadIdx.x;
  if (i < E) atomicAdd(&counts[dst[i]], 1);
}

__global__ __launch_bounds__(256) void k_dinv(const int* __restrict__ counts,
    float* __restrict__ dinv, int N) {
  int i = blockIdx.x * blockDim.x + threadIdx.x;
  if (i < N) dinv[i] = rsqrtf((float)(counts[i] + 1));
}

// ---------------- hierarchical scan ----------------
__global__ __launch_bounds__(256) void k_scan1(const int* __restrict__ counts,
    int* __restrict__ incl, int* __restrict__ bsum, int n) {
  __shared__ int ws[4];
  int t = threadIdx.x;
  int i = blockIdx.x * 256 + t;
  int lane = t & 63, w = t >> 6;
  int v = (i < n) ? counts[i] : 0;
  int s = v;
#pragma unroll
  for (int off = 1; off < 64; off <<= 1) {
    int u = __shfl_up(s, off, 64);
    if (lane >= off) s += u;
  }
  if (lane == 63) ws[w] = s;
  __syncthreads();
  if (t == 0) {
    int acc = 0;
#pragma unroll
    for (int j = 0; j < 4; ++j) { int tmp = ws[j]; ws[j] = acc; acc += tmp; }
  }
  __syncthreads();
  s += ws[w];
  if (i < n) incl[i] = s;
  if (t == 255) bsum[blockIdx.x] = s;
}

__global__ __launch_bounds__(256) void k_scan2(int* __restrict__ bsum, int nb) {
  __shared__ int ws[4];
  int t = threadIdx.x, lane = t & 63, w = t >> 6;
  int v = (t < nb) ? bsum[t] : 0;
  int s = v;
#pragma unroll
  for (int off = 1; off < 64; off <<= 1) {
    int u = __shfl_up(s, off, 64);
    if (lane >= off) s += u;
  }
  if (lane == 63) ws[w] = s;
  __syncthreads();
  if (t == 0) {
    int acc = 0;
#pragma unroll
    for (int j = 0; j < 4; ++j) { int tmp = ws[j]; ws[j] = acc; acc += tmp; }
  }
  __syncthreads();
  s += ws[w];
  if (t < nb) bsum[t] = s - v;   // exclusive
}

__global__ __launch_bounds__(256) void k_scan3(const int* __restrict__ incl,
    const int* __restrict__ boff, int* __restrict__ row_ptr, int n) {
  int i = blockIdx.x * 256 + threadIdx.x;
  if (i < n) row_ptr[i + 1] = incl[i] + boff[i >> 8];
  if (i == 0) row_ptr[0] = 0;
}

// ---------------- CSR fill ----------------
__global__ __launch_bounds__(256) void k_fill(const int* __restrict__ src,
    const int* __restrict__ dst, const int* __restrict__ row_ptr,
    int* __restrict__ cursor, int* __restrict__ col, int E) {
  int i = blockIdx.x * blockDim.x + threadIdx.x;
  if (i < E) {
    int d = dst[i];
    int pos = atomicAdd(&cursor[d], 1);
    col[row_ptr[d] + pos] = src[i];
  }
}

// ---------------- graph boundaries: gstart[g] = first node with batch >= g ----
__global__ __launch_bounds__(256) void k_bound(const int* __restrict__ batch,
    int* __restrict__ gstart, int N, int G) {
  int i = blockIdx.x * 256 + threadIdx.x;
  if (i > N) return;
  int lo = (i == 0) ? 0 : batch[i - 1] + 1;
  int hi = (i == N) ? G : batch[i];
  for (int g = lo; g <= hi; ++g) gstart[g] = i;
}

// ---------------- W transpose + bf16: wt[l][n][k] packed pairs ----------------
__global__ __launch_bounds__(256) void k_wt(const float* __restrict__ W,
    uint* __restrict__ wt, int total) {   // total = L*128*64
  int idx = blockIdx.x * 256 + threadIdx.x;
  if (idx >= total) return;
  int l = idx >> 13;
  int rem = idx & 8191;
  int n = rem >> 6;
  int k2 = rem & 63;
  const float* w = W + (size_t)l * H * H;
  float x0 = w[(size_t)(2 * k2) * H + n];
  float x1 = w[(size_t)(2 * k2 + 1) * H + n];
  wt[idx] = pk_bf16(x0, x1);
}

// ---------------- BN fold: sc = gamma*rsqrt(var+eps), bb = beta - mean*sc ----
__global__ void k_bnparm(const float* __restrict__ bn_sum,
    const float* __restrict__ bn_sq, const float* __restrict__ gamma,
    const float* __restrict__ beta, float* __restrict__ sc,
    float* __restrict__ bb, float invN) {
  int c = threadIdx.x;   // 128
  float mean = bn_sum[c] * invN;
  float var = bn_sq[c] * invN - mean * mean;
  float s = gamma[c] * rsqrtf(var + 1e-5f);
  sc[c] = s;
  bb[c] = beta[c] - mean * s;
}

// ---------------- MFMA GEMM: ms = bf16(dinv * (A' @ W)) ----------------
// A' = FUSED ? (relu(sc*a_bf16+bb)+hold, also written to hnew) : Af (fp32).
// 128x128 tile, 4 waves (2x2) of 64x64, bf16 16x16x32 MFMA, XOR-swizzled LDS.
template <int FUSED>
__global__ __launch_bounds__(256) void k_gemm_mfma(
    const float* __restrict__ Af, const uint* __restrict__ Ap,
    const float* __restrict__ hold, float* __restrict__ hnew,
    const float* __restrict__ sc, const float* __restrict__ bb,
    const uint* __restrict__ wt, uint* __restrict__ ms,
    const float* __restrict__ dinv, int N) {
  __shared__ uint4 smem4[4096];          // 64 KB: sA [0,32K), sB [32K,64K)
  char* smemc = (char*)smem4;
  int t = threadIdx.x;
  int row0 = blockIdx.x * 128;

  // ---- stage A, swizzled (16B granularity) ----
#pragma unroll
  for (int it = 0; it < 8; ++it) {
    int i = t + it * 256;                 // uint4 slots over [128][16]
    int r = i >> 4;
    int c16 = i & 15;
    int c0 = c16 * 8;
    uint4 w4;
    if (FUSED) {
      uint4 av = *(const uint4*)(Ap + (size_t)(row0 + r) * 64 + c16 * 4);
      const float* hrow = hold + (size_t)(row0 + r) * H + c0;
      float4 ho0 = *(const float4*)(hrow);
      float4 ho1 = *(const float4*)(hrow + 4);
      float4 s0 = *(const float4*)(sc + c0), s1 = *(const float4*)(sc + c0 + 4);
      float4 b0 = *(const float4*)(bb + c0), b1 = *(const float4*)(bb + c0 + 4);
      float h0 = fmaxf(s0.x * BLO(av.x) + b0.x, 0.f) + ho0.x;
      float h1 = fmaxf(s0.y * BHI(av.x) + b0.y, 0.f) + ho0.y;
      float h2 = fmaxf(s0.z * BLO(av.y) + b0.z, 0.f) + ho0.z;
      float h3 = fmaxf(s0.w * BHI(av.y) + b0.w, 0.f) + ho0.w;
      float h4 = fmaxf(s1.x * BLO(av.z) + b1.x, 0.f) + ho1.x;
      float h5 = fmaxf(s1.y * BHI(av.z) + b1.y, 0.f) + ho1.y;
      float h6 = fmaxf(s1.z * BLO(av.w) + b1.z, 0.f) + ho1.z;
      float h7 = fmaxf(s1.w * BHI(av.w) + b1.w, 0.f) + ho1.w;
      float* nrow = hnew + (size_t)(row0 + r) * H + c0;
      float4 o0 = {h0, h1, h2, h3}, o1 = {h4, h5, h6, h7};
      *(float4*)nrow = o0;
      *(float4*)(nrow + 4) = o1;
      w4.x = pk_bf16(h0, h1); w4.y = pk_bf16(h2, h3);
      w4.z = pk_bf16(h4, h5); w4.w = pk_bf16(h6, h7);
    } else {
      const float* arow = Af + (size_t)(row0 + r) * H + c0;
      float4 v0 = *(const float4*)arow;
      float4 v1 = *(const float4*)(arow + 4);
      w4.x = pk_bf16(v0.x, v0.y); w4.y = pk_bf16(v0.z, v0.w);
      w4.z = pk_bf16(v1.x, v1.y); w4.w = pk_bf16(v1.z, v1.w);
    }
    int byte = r * 256 + ((c16 * 16) ^ ((r & 7) << 4));
    *(uint4*)(smemc + byte) = w4;
  }
  // ---- stage B: wt bf16 [n][k], swizzled ----
#pragma unroll
  for (int it = 0; it < 8; ++it) {
    int i = t + it * 256;                 // uint4 slots over [128][16]
    int n = i >> 4;
    int k16 = i & 15;
    int byte = 32768 + n * 256 + ((k16 * 16) ^ ((n & 7) << 4));
    *(uint4*)(smemc + byte) = ((const uint4*)wt)[i];
  }
  __syncthreads();

  int wid = t >> 6, l = t & 63;
  int wm = wid >> 1, wn = wid & 1;
  int lr = l & 15, lg = l >> 4;           // frag row/col, k-group

  f32x4 acc[4][4];
#pragma unroll
  for (int mt = 0; mt < 4; ++mt)
#pragma unroll
    for (int nt = 0; nt < 4; ++nt) acc[mt][nt] = (f32x4)0.f;

#pragma unroll
  for (int kk = 0; kk < 4; ++kk) {
    int kbyte = kk * 64 + lg * 16;
    short8 af[4], bf[4];
#pragma unroll
    for (int mt = 0; mt < 4; ++mt) {
      int r = wm * 64 + mt * 16 + lr;
      af[mt] = *(const short8*)(smemc + r * 256 + (kbyte ^ ((r & 7) << 4)));
    }
#pragma unroll
    for (int nt = 0; nt < 4; ++nt) {
      int n = wn * 64 + nt * 16 + lr;
      bf[nt] = *(const short8*)(smemc + 32768 + n * 256 + (kbyte ^ ((n & 7) << 4)));
    }
#pragma unroll
    for (int mt = 0; mt < 4; ++mt)
#pragma unroll
      for (int nt = 0; nt < 4; ++nt)
        acc[mt][nt] = __builtin_amdgcn_mfma_f32_16x16x32_bf16(
            af[mt], bf[nt], acc[mt][nt], 0, 0, 0);
  }
  __syncthreads();   // all LDS reads done; sA space becomes sC

  // ---- epilogue: scale by dinv, bf16, bounce through LDS, coalesced out ----
  float dr[4][4];
#pragma unroll
  for (int mt = 0; mt < 4; ++mt)
#pragma unroll
    for (int j = 0; j < 4; ++j) {
      int grow = row0 + wm * 64 + mt * 16 + lg * 4 + j;
      dr[mt][j] = (grow < N) ? dinv[grow] : 0.f;
    }
#pragma unroll
  for (int mt = 0; mt < 4; ++mt)
#pragma unroll
    for (int nt = 0; nt < 4; ++nt)
#pragma unroll
      for (int j = 0; j < 4; ++j) {
        int lrow = wm * 64 + mt * 16 + lg * 4 + j;
        int lcol = wn * 64 + nt * 16 + lr;
        float val = acc[mt][nt][j] * dr[mt][j];
        *(short*)(smemc + lrow * 256 + lcol * 2) = (short)f2bf(val);
      }
  __syncthreads();
#pragma unroll
  for (int it = 0; it < 8; ++it) {
    int i = t + it * 256;                 // uint4 slots over [128][16]
    int r = i >> 4;
    int c16 = i & 15;
    uint4 v = *(const uint4*)(smemc + r * 256 + c16 * 16);
    ((uint4*)ms)[(size_t)(row0 + r) * 16 + c16] = v;
  }
}

// ------------- aggregate v3: edge-flattened, software-pipelined -------------
// Each wave owns 8 consecutive nodes => one contiguous CSR edge range.
// 2-deep pipeline: consume batch k while ms(k+1) gathers + col(k+2) loads are
// in flight (~17 outstanding). Node boundaries flushed in-register (uniform).
__global__ __launch_bounds__(256) void k_agg(const uint* __restrict__ ms,
    const int* __restrict__ row_ptr, const int* __restrict__ col,
    const float* __restrict__ dinv, const float* __restrict__ bias,
    uint* __restrict__ a, float* __restrict__ bn_sum, float* __restrict__ bn_sq,
    int N) {
  __shared__ float s_sum[128], s_sq[128];
  for (int i = threadIdx.x; i < 128; i += 256) { s_sum[i] = 0.f; s_sq[i] = 0.f; }
  __syncthreads();
  int lane = threadIdx.x & 63;
  int wi = (blockIdx.x * 256 + threadIdx.x) >> 6;
  float b0 = bias[2 * lane], b1 = bias[2 * lane + 1];
  float lsum0 = 0.f, lsq0 = 0.f, lsum1 = 0.f, lsq1 = 0.f;

  int base = wi * 8;
  if (base < N) {
    int vend = (base + 8 < N) ? base + 8 : N;
    int e0 = row_ptr[base];
    int e1 = row_ptr[vend];
    int v = base;
    int end_cur = row_ptr[v + 1];
    float dv = dinv[v];
    uint selfw = ms[(size_t)v * 64 + lane];   // self-loop term, prefetched
    float acc0 = 0.f, acc1 = 0.f;

    auto FLUSH = [&]() {
      float t0 = acc0 + BLO(selfw);
      float t1 = acc1 + BHI(selfw);
      float a0 = fmaxf(dv * t0 + b0, 0.f);
      float a1 = fmaxf(dv * t1 + b1, 0.f);
      uint w = pk_bf16(a0, a1);
      a[(size_t)v * 64 + lane] = w;
      float r0 = BLO(w), r1 = BHI(w);
      lsum0 += r0; lsq0 += r0 * r0;
      lsum1 += r1; lsq1 += r1 * r1;
      ++v;
      if (v < vend) {
        end_cur = row_ptr[v + 1];
        dv = dinv[v];
        selfw = ms[(size_t)v * 64 + lane];
        acc0 = 0.f; acc1 = 0.f;
      }
    };

    int e = e0;
    int total = e1 - e0;
    int nfull = total >> 3;
    int cA[8], cB[8];
    uint wA[8], wB[8];
    if (nfull > 0) {
#pragma unroll
      for (int j = 0; j < 8; ++j) cA[j] = col[e0 + j];
    }
    if (nfull > 1) {
#pragma unroll
      for (int j = 0; j < 8; ++j) cB[j] = col[e0 + 8 + j];
    }
    if (nfull > 0) {
#pragma unroll
      for (int j = 0; j < 8; ++j) wA[j] = ms[(size_t)cA[j] * 64 + lane];
    }
    for (int b = 0; b < nfull; b += 2) {
      // ---- sub-iter A: consume wA (batch b) ----
      if (b + 1 < nfull) {
#pragma unroll
        for (int j = 0; j < 8; ++j) wB[j] = ms[(size_t)cB[j] * 64 + lane];
      }
      if (b + 2 < nfull) {
#pragma unroll
        for (int j = 0; j < 8; ++j) cA[j] = col[e + 16 + j];
      }
#pragma unroll
      for (int j = 0; j < 8; ++j) {
        while (e + j >= end_cur) FLUSH();
        acc0 += BLO(wA[j]); acc1 += BHI(wA[j]);
      }
      e += 8;
      // ---- sub-iter B: consume wB (batch b+1) ----
      if (b + 1 < nfull) {
        if (b + 3 < nfull) {
#pragma unroll
          for (int j = 0; j < 8; ++j) cB[j] = col[e + 16 + j];
        }
        if (b + 2 < nfull) {
#pragma unroll
          for (int j = 0; j < 8; ++j) wA[j] = ms[(size_t)cA[j] * 64 + lane];
        }
#pragma unroll
        for (int j = 0; j < 8; ++j) {
          while (e + j >= end_cur) FLUSH();
          acc0 += BLO(wB[j]); acc1 += BHI(wB[j]);
        }
        e += 8;
      }
    }
    // ---- masked tail batch (<=7 edges), still fully parallel ----
    int rem = e1 - e;
    if (rem > 0) {
      int cT[8];
      uint wT[8];
#pragma unroll
      for (int j = 0; j < 8; ++j) {
        int idx = e + j;
        cT[j] = col[(idx < e1) ? idx : (e1 - 1)];
      }
#pragma unroll
      for (int j = 0; j < 8; ++j) wT[j] = ms[(size_t)cT[j] * 64 + lane];
#pragma unroll
      for (int j = 0; j < 8; ++j) {
        if (j < rem) {
          while (e + j >= end_cur) FLUSH();
          acc0 += BLO(wT[j]); acc1 += BHI(wT[j]);
        }
      }
    }
    while (v < vend) FLUSH();
  }

  atomicAdd(&s_sum[2 * lane], lsum0);
  atomicAdd(&s_sum[2 * lane + 1], lsum1);
  atomicAdd(&s_sq[2 * lane], lsq0);
  atomicAdd(&s_sq[2 * lane + 1], lsq1);
  __syncthreads();
  for (int i = threadIdx.x; i < 128; i += 256) {
    atomicAdd(&bn_sum[i], s_sum[i]);
    atomicAdd(&bn_sq[i], s_sq[i]);
  }
}

// ------- fused readout: one wave per graph, BN+relu+residual+mean+linear ------
__global__ __launch_bounds__(256) void k_poolout(const uint* __restrict__ a,
    const float* __restrict__ hold, const float* __restrict__ sc,
    const float* __restrict__ bb, const int* __restrict__ gstart,
    const float* __restrict__ lw, const float* __restrict__ lb,
    float* __restrict__ out, int G) {
  int g = (blockIdx.x * 256 + threadIdx.x) >> 6;
  int lane = threadIdx.x & 63;
  if (g >= G) return;
  int s0 = gstart[g], s1 = gstart[g + 1];
  float2 s2 = *(const float2*)(sc + 2 * lane);
  float2 b2 = *(const float2*)(bb + 2 * lane);
  float acc0 = 0.f, acc1 = 0.f;
  for (int v = s0; v < s1; ++v) {
    uint av = a[(size_t)v * 64 + lane];
    float2 hv = *(const float2*)(hold + (size_t)v * H + 2 * lane);
    acc0 += fmaxf(s2.x * BLO(av) + b2.x, 0.f) + hv.x;
    acc1 += fmaxf(s2.y * BHI(av) + b2.y, 0.f) + hv.y;
  }
  float inv = 1.f / fmaxf((float)(s1 - s0), 1.f);
  float2 w2 = *(const float2*)(lw + 2 * lane);
  float s = acc0 * inv * w2.x + acc1 * inv * w2.y;
#pragma unroll
  for (int off = 32; off > 0; off >>= 1) s += __shfl_down(s, off, 64);
  if (lane == 0) out[g] = 1.f / (1.f + expf(-(s + lb[0])));
}

extern "C" void kernel_launch(void* const* d_in, const int* in_sizes, int n_in,
                              void* d_out, int out_size, void* d_ws, size_t ws_size,
                              hipStream_t stream) {
  const int* x      = (const int*)d_in[0];
  const int* ei     = (const int*)d_in[1];
  const int* batch  = (const int*)d_in[2];
  const float* emb  = (const float*)d_in[3];
  const float* convW = (const float*)d_in[4];
  const float* convB = (const float*)d_in[5];
  const float* gamma = (const float*)d_in[6];
  const float* beta  = (const float*)d_in[7];
  const float* lw    = (const float*)d_in[8];
  const float* lb    = (const float*)d_in[9];
  float* out = (float*)d_out;

  const int N = in_sizes[2];
  const int E = in_sizes[1] / 2;
  const int G = out_size;
  const int MAXV = in_sizes[3] / (FEAT * H);
  const int L = in_sizes[4] / (H * H);
  const int Npad = (N + 127) & ~127;

  const int* srcp = ei;
  const int* dstp = ei + E;

  char* p = (char*)d_ws;
  auto alloc = [&](size_t bytes) { char* r = p; p += (bytes + 255) & ~255ull; return r; };
  float* h    = (float*)alloc((size_t)Npad * H * 4);
  uint*  ms   = (uint*)alloc((size_t)Npad * 64 * 4);   // bf16x2 packed, pre-scaled
  uint*  a    = (uint*)alloc((size_t)Npad * 64 * 4);   // bf16x2 packed activations
  float* dinv = (float*)alloc((size_t)N * 4);
  int* row_ptr = (int*)alloc((size_t)(N + 1) * 4);
  int* col     = (int*)alloc((size_t)E * 4);
  int* incl    = (int*)alloc((size_t)N * 4);
  int* bsum    = (int*)alloc(256 * 4);
  uint* wt     = (uint*)alloc((size_t)L * H * 64 * 4); // WT bf16 [l][n][k/2]
  float* scb   = (float*)alloc((size_t)L * H * 4);
  float* bbb   = (float*)alloc((size_t)L * H * 4);
  int* gstart  = (int*)alloc((size_t)(G + 1) * 4);
  char* z0 = p;
  int* counts   = (int*)alloc((size_t)N * 4);
  int* cursor   = (int*)alloc((size_t)N * 4);
  float* bn_sum = (float*)alloc((size_t)L * H * 4);
  float* bn_sq  = (float*)alloc((size_t)L * H * 4);
  size_t zbytes = (size_t)(p - z0);

  hipMemsetAsync(z0, 0, zbytes, stream);

  const int nb = (N + 255) / 256;
  const float invN = 1.0f / (float)N;

  // graph prep
  k_atom<<<Npad / 4, 256, 0, stream>>>(x, emb, h, N, Npad, MAXV);
  k_count<<<(E + 255) / 256, 256, 0, stream>>>(dstp, counts, E);
  k_dinv<<<(N + 255) / 256, 256, 0, stream>>>(counts, dinv, N);
  k_scan1<<<nb, 256, 0, stream>>>(counts, incl, bsum, N);
  k_scan2<<<1, 256, 0, stream>>>(bsum, nb);
  k_scan3<<<nb, 256, 0, stream>>>(incl, bsum, row_ptr, N);
  k_fill<<<(E + 255) / 256, 256, 0, stream>>>(srcp, dstp, row_ptr, cursor, col, E);
  k_bound<<<(N + 256) / 256, 256, 0, stream>>>(batch, gstart, N, G);
  k_wt<<<(L * H * 64 + 255) / 256, 256, 0, stream>>>(convW, wt, L * H * 64);

  const int aggWaves = (N + 7) / 8;
  const int aggBlocks = (aggWaves + 3) / 4;

  // layers
  for (int l = 0; l < L; ++l) {
    if (l == 0) {
      k_gemm_mfma<0><<<Npad / 128, 256, 0, stream>>>(
          h, nullptr, nullptr, nullptr, nullptr, nullptr,
          wt, ms, dinv, N);
    } else {
      k_gemm_mfma<1><<<Npad / 128, 256, 0, stream>>>(
          nullptr, a, h, h, scb + (size_t)(l - 1) * H, bbb + (size_t)(l - 1) * H,
          wt + (size_t)l * H * 64, ms, dinv, N);
    }
    k_agg<<<aggBlocks, 256, 0, stream>>>(ms, row_ptr, col, dinv, convB + (size_t)l * H,
                                         a, bn_sum + (size_t)l * H, bn_sq + (size_t)l * H, N);
    k_bnparm<<<1, 128, 0, stream>>>(bn_sum + (size_t)l * H, bn_sq + (size_t)l * H,
                                    gamma + (size_t)l * H, beta + (size_t)l * H,
                                    scb + (size_t)l * H, bbb + (size_t)l * H, invN);
  }

  // fused readout (final BN + relu + residual + mean-pool + linear + sigmoid)
  k_poolout<<<(G + 3) / 4, 256, 0, stream>>>(a, h, scb + (size_t)(L - 1) * H,
                                             bbb + (size_t)(L - 1) * H, gstart,
                                             lw, lb, out, G);
}

// Round 7
// 448.531 us; speedup vs baseline: 2.1863x; 1.0999x over previous
//
#include <hip/hip_runtime.h>
#include <hip/hip_bf16.h>
#include <math.h>

#define H 128
#define FEAT 9

typedef unsigned int uint;
typedef __attribute__((ext_vector_type(8))) short short8;   // 8 bf16 = 4 VGPR
typedef __attribute__((ext_vector_type(4))) float f32x4;

// round-to-nearest-even f32 -> bf16 (finite inputs)
__device__ inline uint f2bf(float f) {
  uint u = __float_as_uint(f);
  return (u + 0x7FFF + ((u >> 16) & 1)) >> 16;
}
__device__ inline uint pk_bf16(float a, float b) {
  return f2bf(a) | (f2bf(b) << 16);
}
#define BLO(u) __uint_as_float((u) << 16)
#define BHI(u) __uint_as_float((u) & 0xFFFF0000u)

// ---------------- Atom encoder: h[v] = sum_f emb[f, x[v,f], :] ----------------
__global__ __launch_bounds__(256) void k_atom(const int* __restrict__ x,
    const float* __restrict__ emb, float* __restrict__ h,
    int N, int Npad, int maxv) {
  int wid = (blockIdx.x * blockDim.x + threadIdx.x) >> 6;
  int lane = threadIdx.x & 63;
  if (wid >= Npad) return;
  float a0 = 0.f, a1 = 0.f;
  if (wid < N) {
    const int* xr = x + (size_t)wid * FEAT;
#pragma unroll
    for (int f = 0; f < FEAT; ++f) {
      int id = xr[f];
      const float* e = emb + ((size_t)f * maxv + id) * H;
      a0 += e[lane];
      a1 += e[lane + 64];
    }
  }
  h[(size_t)wid * H + lane] = a0;
  h[(size_t)wid * H + 64 + lane] = a1;
}

// ---------------- degree count (by dst) ----------------
__global__ __launch_bounds__(256) void k_count(const int* __restrict__ dst,
    int* __restrict__ counts, int E) {
  int i = blockIdx.x * blockDim.x + threadIdx.x;
  if (i < E) atomicAdd(&counts[dst[i]], 1);
}

// dinv + padded counts (multiple of 8, min 8)
__global__ __launch_bounds__(256) void k_dinv(const int* __restrict__ counts,
    float* __restrict__ dinv, int* __restrict__ pcnt, int N) {
  int i = blockIdx.x * blockDim.x + threadIdx.x;
  if (i < N) {
    int c = counts[i];
    dinv[i] = rsqrtf((float)(c + 1));
    int p = (c + 7) & ~7;
    pcnt[i] = (p < 8) ? 8 : p;
  }
}

// ---------------- hierarchical scan (over padded counts) ----------------
__global__ __launch_bounds__(256) void k_scan1(const int* __restrict__ counts,
    int* __restrict__ incl, int* __restrict__ bsum, int n) {
  __shared__ int ws[4];
  int t = threadIdx.x;
  int i = blockIdx.x * 256 + t;
  int lane = t & 63, w = t >> 6;
  int v = (i < n) ? counts[i] : 0;
  int s = v;
#pragma unroll
  for (int off = 1; off < 64; off <<= 1) {
    int u = __shfl_up(s, off, 64);
    if (lane >= off) s += u;
  }
  if (lane == 63) ws[w] = s;
  __syncthreads();
  if (t == 0) {
    int acc = 0;
#pragma unroll
    for (int j = 0; j < 4; ++j) { int tmp = ws[j]; ws[j] = acc; acc += tmp; }
  }
  __syncthreads();
  s += ws[w];
  if (i < n) incl[i] = s;
  if (t == 255) bsum[blockIdx.x] = s;
}

__global__ __launch_bounds__(256) void k_scan2(int* __restrict__ bsum, int nb) {
  __shared__ int ws[4];
  int t = threadIdx.x, lane = t & 63, w = t >> 6;
  int v = (t < nb) ? bsum[t] : 0;
  int s = v;
#pragma unroll
  for (int off = 1; off < 64; off <<= 1) {
    int u = __shfl_up(s, off, 64);
    if (lane >= off) s += u;
  }
  if (lane == 63) ws[w] = s;
  __syncthreads();
  if (t == 0) {
    int acc = 0;
#pragma unroll
    for (int j = 0; j < 4; ++j) { int tmp = ws[j]; ws[j] = acc; acc += tmp; }
  }
  __syncthreads();
  s += ws[w];
  if (t < nb) bsum[t] = s - v;   // exclusive
}

__global__ __launch_bounds__(256) void k_scan3(const int* __restrict__ incl,
    const int* __restrict__ boff, int* __restrict__ row_ptr, int n) {
  int i = blockIdx.x * 256 + threadIdx.x;
  if (i < n) row_ptr[i + 1] = incl[i] + boff[i >> 8];
  if (i == 0) row_ptr[0] = 0;
}

// ---------------- CSR fill (into padded layout) ----------------
__global__ __launch_bounds__(256) void k_fill(const int* __restrict__ src,
    const int* __restrict__ dst, const int* __restrict__ row_ptr,
    int* __restrict__ cursor, int* __restrict__ col, int E) {
  int i = blockIdx.x * blockDim.x + threadIdx.x;
  if (i < E) {
    int d = dst[i];
    int pos = atomicAdd(&cursor[d], 1);
    col[row_ptr[d] + pos] = src[i];
  }
}

// ---------------- sentinel pad fill: col[rp[v]+deg .. rp[v+1]) = N ----------------
__global__ __launch_bounds__(256) void k_pad(const int* __restrict__ counts,
    const int* __restrict__ rp, int* __restrict__ col, int N) {
  int v = blockIdx.x * 256 + threadIdx.x;
  if (v >= N) return;
  int s = rp[v] + counts[v];
  int e = rp[v + 1];
  for (int i = s; i < e; ++i) col[i] = N;   // row N of ms is all-zero
}

// ---------------- graph boundaries: gstart[g] = first node with batch >= g ----
__global__ __launch_bounds__(256) void k_bound(const int* __restrict__ batch,
    int* __restrict__ gstart, int N, int G) {
  int i = blockIdx.x * 256 + threadIdx.x;
  if (i > N) return;
  int lo = (i == 0) ? 0 : batch[i - 1] + 1;
  int hi = (i == N) ? G : batch[i];
  for (int g = lo; g <= hi; ++g) gstart[g] = i;
}

// ---------------- W transpose + bf16: wt[l][n][k] packed pairs ----------------
__global__ __launch_bounds__(256) void k_wt(const float* __restrict__ W,
    uint* __restrict__ wt, int total) {   // total = L*128*64
  int idx = blockIdx.x * 256 + threadIdx.x;
  if (idx >= total) return;
  int l = idx >> 13;
  int rem = idx & 8191;
  int n = rem >> 6;
  int k2 = rem & 63;
  const float* w = W + (size_t)l * H * H;
  float x0 = w[(size_t)(2 * k2) * H + n];
  float x1 = w[(size_t)(2 * k2 + 1) * H + n];
  wt[idx] = pk_bf16(x0, x1);
}

// ---------------- BN fold: sc = gamma*rsqrt(var+eps), bb = beta - mean*sc ----
__global__ void k_bnparm(const float* __restrict__ bn_sum,
    const float* __restrict__ bn_sq, const float* __restrict__ gamma,
    const float* __restrict__ beta, float* __restrict__ sc,
    float* __restrict__ bb, float invN) {
  int c = threadIdx.x;   // 128
  float mean = bn_sum[c] * invN;
  float var = bn_sq[c] * invN - mean * mean;
  float s = gamma[c] * rsqrtf(var + 1e-5f);
  sc[c] = s;
  bb[c] = beta[c] - mean * s;
}

// ---------------- MFMA GEMM: ms = bf16(dinv * (A' @ W)) ----------------
template <int FUSED>
__global__ __launch_bounds__(256) void k_gemm_mfma(
    const float* __restrict__ Af, const uint* __restrict__ Ap,
    const float* __restrict__ hold, float* __restrict__ hnew,
    const float* __restrict__ sc, const float* __restrict__ bb,
    const uint* __restrict__ wt, uint* __restrict__ ms,
    const float* __restrict__ dinv, int N) {
  __shared__ uint4 smem4[4096];          // 64 KB: sA [0,32K), sB [32K,64K)
  char* smemc = (char*)smem4;
  int t = threadIdx.x;
  int row0 = blockIdx.x * 128;

  // ---- stage A, swizzled (16B granularity) ----
#pragma unroll
  for (int it = 0; it < 8; ++it) {
    int i = t + it * 256;                 // uint4 slots over [128][16]
    int r = i >> 4;
    int c16 = i & 15;
    int c0 = c16 * 8;
    uint4 w4;
    if (FUSED) {
      uint4 av = *(const uint4*)(Ap + (size_t)(row0 + r) * 64 + c16 * 4);
      const float* hrow = hold + (size_t)(row0 + r) * H + c0;
      float4 ho0 = *(const float4*)(hrow);
      float4 ho1 = *(const float4*)(hrow + 4);
      float4 s0 = *(const float4*)(sc + c0), s1 = *(const float4*)(sc + c0 + 4);
      float4 b0 = *(const float4*)(bb + c0), b1 = *(const float4*)(bb + c0 + 4);
      float h0 = fmaxf(s0.x * BLO(av.x) + b0.x, 0.f) + ho0.x;
      float h1 = fmaxf(s0.y * BHI(av.x) + b0.y, 0.f) + ho0.y;
      float h2 = fmaxf(s0.z * BLO(av.y) + b0.z, 0.f) + ho0.z;
      float h3 = fmaxf(s0.w * BHI(av.y) + b0.w, 0.f) + ho0.w;
      float h4 = fmaxf(s1.x * BLO(av.z) + b1.x, 0.f) + ho1.x;
      float h5 = fmaxf(s1.y * BHI(av.z) + b1.y, 0.f) + ho1.y;
      float h6 = fmaxf(s1.z * BLO(av.w) + b1.z, 0.f) + ho1.z;
      float h7 = fmaxf(s1.w * BHI(av.w) + b1.w, 0.f) + ho1.w;
      float* nrow = hnew + (size_t)(row0 + r) * H + c0;
      float4 o0 = {h0, h1, h2, h3}, o1 = {h4, h5, h6, h7};
      *(float4*)nrow = o0;
      *(float4*)(nrow + 4) = o1;
      w4.x = pk_bf16(h0, h1); w4.y = pk_bf16(h2, h3);
      w4.z = pk_bf16(h4, h5); w4.w = pk_bf16(h6, h7);
    } else {
      const float* arow = Af + (size_t)(row0 + r) * H + c0;
      float4 v0 = *(const float4*)arow;
      float4 v1 = *(const float4*)(arow + 4);
      w4.x = pk_bf16(v0.x, v0.y); w4.y = pk_bf16(v0.z, v0.w);
      w4.z = pk_bf16(v1.x, v1.y); w4.w = pk_bf16(v1.z, v1.w);
    }
    int byte = r * 256 + ((c16 * 16) ^ ((r & 7) << 4));
    *(uint4*)(smemc + byte) = w4;
  }
  // ---- stage B: wt bf16 [n][k], swizzled ----
#pragma unroll
  for (int it = 0; it < 8; ++it) {
    int i = t + it * 256;                 // uint4 slots over [128][16]
    int n = i >> 4;
    int k16 = i & 15;
    int byte = 32768 + n * 256 + ((k16 * 16) ^ ((n & 7) << 4));
    *(uint4*)(smemc + byte) = ((const uint4*)wt)[i];
  }
  __syncthreads();

  int wid = t >> 6, l = t & 63;
  int wm = wid >> 1, wn = wid & 1;
  int lr = l & 15, lg = l >> 4;           // frag row/col, k-group

  f32x4 acc[4][4];
#pragma unroll
  for (int mt = 0; mt < 4; ++mt)
#pragma unroll
    for (int nt = 0; nt < 4; ++nt) acc[mt][nt] = (f32x4)0.f;

#pragma unroll
  for (int kk = 0; kk < 4; ++kk) {
    int kbyte = kk * 64 + lg * 16;
    short8 af[4], bf[4];
#pragma unroll
    for (int mt = 0; mt < 4; ++mt) {
      int r = wm * 64 + mt * 16 + lr;
      af[mt] = *(const short8*)(smemc + r * 256 + (kbyte ^ ((r & 7) << 4)));
    }
#pragma unroll
    for (int nt = 0; nt < 4; ++nt) {
      int n = wn * 64 + nt * 16 + lr;
      bf[nt] = *(const short8*)(smemc + 32768 + n * 256 + (kbyte ^ ((n & 7) << 4)));
    }
#pragma unroll
    for (int mt = 0; mt < 4; ++mt)
#pragma unroll
      for (int nt = 0; nt < 4; ++nt)
        acc[mt][nt] = __builtin_amdgcn_mfma_f32_16x16x32_bf16(
            af[mt], bf[nt], acc[mt][nt], 0, 0, 0);
  }
  __syncthreads();   // all LDS reads done; sA space becomes sC

  // ---- epilogue: scale by dinv, bf16, bounce through LDS, coalesced out ----
  float dr[4][4];
#pragma unroll
  for (int mt = 0; mt < 4; ++mt)
#pragma unroll
    for (int j = 0; j < 4; ++j) {
      int grow = row0 + wm * 64 + mt * 16 + lg * 4 + j;
      dr[mt][j] = (grow < N) ? dinv[grow] : 0.f;
    }
#pragma unroll
  for (int mt = 0; mt < 4; ++mt)
#pragma unroll
    for (int nt = 0; nt < 4; ++nt)
#pragma unroll
      for (int j = 0; j < 4; ++j) {
        int lrow = wm * 64 + mt * 16 + lg * 4 + j;
        int lcol = wn * 64 + nt * 16 + lr;
        float val = acc[mt][nt][j] * dr[mt][j];
        *(short*)(smemc + lrow * 256 + lcol * 2) = (short)f2bf(val);
      }
  __syncthreads();
#pragma unroll
  for (int it = 0; it < 8; ++it) {
    int i = t + it * 256;                 // uint4 slots over [128][16]
    int r = i >> 4;
    int c16 = i & 15;
    uint4 v = *(const uint4*)(smemc + r * 256 + c16 * 16);
    ((uint4*)ms)[(size_t)(row0 + r) * 16 + c16] = v;
  }
}

// ------------- aggregate v4: padded CSR, branch-free batches, deep pipeline ---
// Node segments padded to multiples of 8 (sentinel col = N -> zero row).
// Per batch: 1 uniform flush check. col via 16-wide lane chunks (1 load / 2
// batches). Gathers 2 batches ahead, mod-3 slots, 6-phase unrolled loop.
__global__ __launch_bounds__(256) void k_agg(const uint* __restrict__ ms,
    const int* __restrict__ rp, const int* __restrict__ col,
    const float* __restrict__ dinv, const float* __restrict__ bias,
    uint* __restrict__ a, float* __restrict__ bn_sum, float* __restrict__ bn_sq,
    int N) {
  __shared__ float s_sum[128], s_sq[128];
  for (int i = threadIdx.x; i < 128; i += 256) { s_sum[i] = 0.f; s_sq[i] = 0.f; }
  __syncthreads();
  int lane = threadIdx.x & 63;
  int wi = (blockIdx.x * 256 + threadIdx.x) >> 6;
  float b0 = bias[2 * lane], b1 = bias[2 * lane + 1];
  float lsum0 = 0.f, lsq0 = 0.f, lsum1 = 0.f, lsq1 = 0.f;

  int base = wi * 8;
  if (base < N) {
    int vend = (base + 8 < N) ? base + 8 : N;
    int nv = vend - base;
    // one-shot vector loads of group metadata
    int rpi = base + lane; if (rpi > vend) rpi = vend;
    int rp_l = rp[rpi];
    int dvi = base + (lane & 7); if (dvi >= N) dvi = N - 1;
    float dv_l = dinv[dvi];
    // self-loop rows (contiguous) all issued upfront
    int sb1 = base + 1 < N ? base + 1 : N;
    int sb2 = base + 2 < N ? base + 2 : N;
    int sb3 = base + 3 < N ? base + 3 : N;
    int sb4 = base + 4 < N ? base + 4 : N;
    int sb5 = base + 5 < N ? base + 5 : N;
    int sb6 = base + 6 < N ? base + 6 : N;
    int sb7 = base + 7 < N ? base + 7 : N;
    uint sw0 = ms[(size_t)base * 64 + lane];
    uint sw1 = ms[(size_t)sb1 * 64 + lane];
    uint sw2 = ms[(size_t)sb2 * 64 + lane];
    uint sw3 = ms[(size_t)sb3 * 64 + lane];
    uint sw4 = ms[(size_t)sb4 * 64 + lane];
    uint sw5 = ms[(size_t)sb5 * 64 + lane];
    uint sw6 = ms[(size_t)sb6 * 64 + lane];
    uint sw7 = ms[(size_t)sb7 * 64 + lane];

    int e0 = __shfl(rp_l, 0, 64);
    int e1 = __shfl(rp_l, nv, 64);
    int j = 0, v = base;
    int end_cur = __shfl(rp_l, 1, 64);
    float dv = __shfl(dv_l, 0, 64);
    float acc0 = 0.f, acc1 = 0.f;
    int e = e0;
    int nb8 = (e1 - e0) >> 3;

#define FLUSHN() do { \
    uint sw = sw0; \
    sw = (j == 1) ? sw1 : sw; sw = (j == 2) ? sw2 : sw; \
    sw = (j == 3) ? sw3 : sw; sw = (j == 4) ? sw4 : sw; \
    sw = (j == 5) ? sw5 : sw; sw = (j == 6) ? sw6 : sw; \
    sw = (j == 7) ? sw7 : sw; \
    float a0 = fmaxf(dv * (acc0 + BLO(sw)) + b0, 0.f); \
    float a1 = fmaxf(dv * (acc1 + BHI(sw)) + b1, 0.f); \
    uint wpk = pk_bf16(a0, a1); \
    a[(size_t)v * 64 + lane] = wpk; \
    float r0 = BLO(wpk), r1 = BHI(wpk); \
    lsum0 += r0; lsq0 += r0 * r0; lsum1 += r1; lsq1 += r1 * r1; \
    ++v; ++j; \
    if (v < vend) { \
      end_cur = __shfl(rp_l, j + 1, 64); \
      dv = __shfl(dv_l, j, 64); \
      acc0 = 0.f; acc1 = 0.f; \
    } \
  } while (0)

#define COL16(off) col[(off) + (lane & 15)]
#define GATHER(W, CU, HALF) do { \
    _Pragma("unroll") \
    for (int jj = 0; jj < 8; ++jj) { \
      int u = __shfl((int)(CU), (HALF) * 8 + jj, 64); \
      W[jj] = ms[(size_t)u * 64 + lane]; \
    } \
  } while (0)
#define STEP(W) do { \
    _Pragma("unroll") \
    for (int jj = 0; jj < 8; ++jj) { acc0 += BLO(W[jj]); acc1 += BHI(W[jj]); } \
    e += 8; \
    if (e == end_cur) FLUSHN(); \
  } while (0)

    uint cu0 = 0, cu1 = 0, cu2 = 0;
    uint w0[8], w1[8], w2[8];
    cu0 = COL16(e0);                               // batches 0,1
    if (nb8 > 2) cu1 = COL16(e0 + 16);             // batches 2,3
    GATHER(w0, cu0, 0);                            // batch 0
    if (nb8 > 1) GATHER(w1, cu0, 1);               // batch 1

    for (int k = 0; k < nb8; k += 6) {
      if (k + 4 < nb8) cu2 = COL16(e0 + (k + 4) * 8);   // batches k+4,k+5
      if (k + 2 < nb8) GATHER(w2, cu1, 0);              // batch k+2
      STEP(w0);                                          // batch k
      if (k + 3 < nb8) GATHER(w0, cu1, 1);              // batch k+3
      if (k + 1 < nb8) STEP(w1);                        // batch k+1
      if (k + 6 < nb8) cu0 = COL16(e0 + (k + 6) * 8);   // batches k+6,k+7
      if (k + 4 < nb8) GATHER(w1, cu2, 0);              // batch k+4
      if (k + 2 < nb8) STEP(w2);                        // batch k+2
      if (k + 5 < nb8) GATHER(w2, cu2, 1);              // batch k+5
      if (k + 3 < nb8) STEP(w0);                        // batch k+3
      if (k + 8 < nb8) cu1 = COL16(e0 + (k + 8) * 8);   // batches k+8,k+9
      if (k + 6 < nb8) GATHER(w0, cu0, 0);              // batch k+6
      if (k + 4 < nb8) STEP(w1);                        // batch k+4
      if (k + 7 < nb8) GATHER(w1, cu0, 1);              // batch k+7
      if (k + 5 < nb8) STEP(w2);                        // batch k+5
    }
#undef FLUSHN
#undef COL16
#undef GATHER
#undef STEP
  }

  atomicAdd(&s_sum[2 * lane], lsum0);
  atomicAdd(&s_sum[2 * lane + 1], lsum1);
  atomicAdd(&s_sq[2 * lane], lsq0);
  atomicAdd(&s_sq[2 * lane + 1], lsq1);
  __syncthreads();
  for (int i = threadIdx.x; i < 128; i += 256) {
    atomicAdd(&bn_sum[i], s_sum[i]);
    atomicAdd(&bn_sq[i], s_sq[i]);
  }
}

// ------- fused readout: one wave per graph, BN+relu+residual+mean+linear ------
__global__ __launch_bounds__(256) void k_poolout(const uint* __restrict__ a,
    const float* __restrict__ hold, const float* __restrict__ sc,
    const float* __restrict__ bb, const int* __restrict__ gstart,
    const float* __restrict__ lw, const float* __restrict__ lb,
    float* __restrict__ out, int G) {
  int g = (blockIdx.x * 256 + threadIdx.x) >> 6;
  int lane = threadIdx.x & 63;
  if (g >= G) return;
  int s0 = gstart[g], s1 = gstart[g + 1];
  float2 s2 = *(const float2*)(sc + 2 * lane);
  float2 b2 = *(const float2*)(bb + 2 * lane);
  float acc0 = 0.f, acc1 = 0.f;
  for (int v = s0; v < s1; ++v) {
    uint av = a[(size_t)v * 64 + lane];
    float2 hv = *(const float2*)(hold + (size_t)v * H + 2 * lane);
    acc0 += fmaxf(s2.x * BLO(av) + b2.x, 0.f) + hv.x;
    acc1 += fmaxf(s2.y * BHI(av) + b2.y, 0.f) + hv.y;
  }
  float inv = 1.f / fmaxf((float)(s1 - s0), 1.f);
  float2 w2 = *(const float2*)(lw + 2 * lane);
  float s = acc0 * inv * w2.x + acc1 * inv * w2.y;
#pragma unroll
  for (int off = 32; off > 0; off >>= 1) s += __shfl_down(s, off, 64);
  if (lane == 0) out[g] = 1.f / (1.f + expf(-(s + lb[0])));
}

extern "C" void kernel_launch(void* const* d_in, const int* in_sizes, int n_in,
                              void* d_out, int out_size, void* d_ws, size_t ws_size,
                              hipStream_t stream) {
  const int* x      = (const int*)d_in[0];
  const int* ei     = (const int*)d_in[1];
  const int* batch  = (const int*)d_in[2];
  const float* emb  = (const float*)d_in[3];
  const float* convW = (const float*)d_in[4];
  const float* convB = (const float*)d_in[5];
  const float* gamma = (const float*)d_in[6];
  const float* beta  = (const float*)d_in[7];
  const float* lw    = (const float*)d_in[8];
  const float* lb    = (const float*)d_in[9];
  float* out = (float*)d_out;

  const int N = in_sizes[2];
  const int E = in_sizes[1] / 2;
  const int G = out_size;
  const int MAXV = in_sizes[3] / (FEAT * H);
  const int L = in_sizes[4] / (H * H);
  const int Npad = (N + 128) & ~127;     // guarantees zero row N exists

  const int* srcp = ei;
  const int* dstp = ei + E;

  char* p = (char*)d_ws;
  auto alloc = [&](size_t bytes) { char* r = p; p += (bytes + 255) & ~255ull; return r; };
  float* h    = (float*)alloc((size_t)Npad * H * 4);
  uint*  ms   = (uint*)alloc((size_t)Npad * 64 * 4);   // bf16x2 packed, pre-scaled
  uint*  a    = (uint*)alloc((size_t)Npad * 64 * 4);   // bf16x2 packed activations
  float* dinv = (float*)alloc((size_t)N * 4);
  int* row_ptr = (int*)alloc((size_t)(N + 1) * 4);
  int* col     = (int*)alloc(((size_t)E + 8 * (size_t)N + 64) * 4);  // padded CSR
  int* pcnt    = (int*)alloc((size_t)N * 4);
  int* incl    = (int*)alloc((size_t)N * 4);
  int* bsum    = (int*)alloc(256 * 4);
  uint* wt     = (uint*)alloc((size_t)L * H * 64 * 4); // WT bf16 [l][n][k/2]
  float* scb   = (float*)alloc((size_t)L * H * 4);
  float* bbb   = (float*)alloc((size_t)L * H * 4);
  int* gstart  = (int*)alloc((size_t)(G + 1) * 4);
  char* z0 = p;
  int* counts   = (int*)alloc((size_t)N * 4);
  int* cursor   = (int*)alloc((size_t)N * 4);
  float* bn_sum = (float*)alloc((size_t)L * H * 4);
  float* bn_sq  = (float*)alloc((size_t)L * H * 4);
  size_t zbytes = (size_t)(p - z0);

  hipMemsetAsync(z0, 0, zbytes, stream);

  const int nb = (N + 255) / 256;
  const float invN = 1.0f / (float)N;

  // graph prep
  k_atom<<<Npad / 4, 256, 0, stream>>>(x, emb, h, N, Npad, MAXV);
  k_count<<<(E + 255) / 256, 256, 0, stream>>>(dstp, counts, E);
  k_dinv<<<(N + 255) / 256, 256, 0, stream>>>(counts, dinv, pcnt, N);
  k_scan1<<<nb, 256, 0, stream>>>(pcnt, incl, bsum, N);
  k_scan2<<<1, 256, 0, stream>>>(bsum, nb);
  k_scan3<<<nb, 256, 0, stream>>>(incl, bsum, row_ptr, N);
  k_fill<<<(E + 255) / 256, 256, 0, stream>>>(srcp, dstp, row_ptr, cursor, col, E);
  k_pad<<<nb, 256, 0, stream>>>(counts, row_ptr, col, N);
  k_bound<<<(N + 256) / 256, 256, 0, stream>>>(batch, gstart, N, G);
  k_wt<<<(L * H * 64 + 255) / 256, 256, 0, stream>>>(convW, wt, L * H * 64);

  const int aggWaves = (N + 7) / 8;
  const int aggBlocks = (aggWaves + 3) / 4;

  // layers
  for (int l = 0; l < L; ++l) {
    if (l == 0) {
      k_gemm_mfma<0><<<Npad / 128, 256, 0, stream>>>(
          h, nullptr, nullptr, nullptr, nullptr, nullptr,
          wt, ms, dinv, N);
    } else {
      k_gemm_mfma<1><<<Npad / 128, 256, 0, stream>>>(
          nullptr, a, h, h, scb + (size_t)(l - 1) * H, bbb + (size_t)(l - 1) * H,
          wt + (size_t)l * H * 64, ms, dinv, N);
    }
    k_agg<<<aggBlocks, 256, 0, stream>>>(ms, row_ptr, col, dinv, convB + (size_t)l * H,
                                         a, bn_sum + (size_t)l * H, bn_sq + (size_t)l * H, N);
    k_bnparm<<<1, 128, 0, stream>>>(bn_sum + (size_t)l * H, bn_sq + (size_t)l * H,
                                    gamma + (size_t)l * H, beta + (size_t)l * H,
                                    scb + (size_t)l * H, bbb + (size_t)l * H, invN);
  }

  // fused readout (final BN + relu + residual + mean-pool + linear + sigmoid)
  k_poolout<<<(G + 3) / 4, 256, 0, stream>>>(a, h, scb + (size_t)(L - 1) * H,
                                             bbb + (size_t)(L - 1) * H, gstart,
                                             lw, lb, out, G);
}